// Round 6
// baseline (2347.194 us; speedup 1.0000x reference)
//
#include <hip/hip_runtime.h>
#include <math.h>

typedef unsigned short u16;
typedef __attribute__((ext_vector_type(8))) short bf8;    // 8 bf16 in 4 VGPRs
typedef __attribute__((ext_vector_type(8))) unsigned short u16x8;
typedef __attribute__((ext_vector_type(4))) float f32x4;

constexpr int NB = 32;      // batch
constexpr int NP = 196;     // pixels
constexpr int NE = 2048;    // encoder dim
constexpr int ED = 512;     // embedding dim
constexpr int HH = 512;     // hidden
constexpr int AA = 512;     // attention dim
constexpr int NV = 10000;   // vocab
constexpr int NT = 20;      // timesteps

__device__ inline u16 f2bf(float f) {
    unsigned u = __builtin_bit_cast(unsigned, f);
    u += 0x7fffu + ((u >> 16) & 1u);          // RNE
    return (u16)(u >> 16);
}
__device__ inline float bf2f(u16 h) {
    return __builtin_bit_cast(float, (unsigned)h << 16);
}
__device__ inline void cvt8(const float* __restrict__ s, u16* __restrict__ d) {
    float4 v0 = *(const float4*)s, v1 = *(const float4*)(s + 4);
    u16x8 o;
    o[0] = f2bf(v0.x); o[1] = f2bf(v0.y); o[2] = f2bf(v0.z); o[3] = f2bf(v0.w);
    o[4] = f2bf(v1.x); o[5] = f2bf(v1.y); o[6] = f2bf(v1.z); o[7] = f2bf(v1.w);
    *(u16x8*)d = o;
}

// async global->LDS, 16 bytes per lane (global_load_lds_dwordx4)
__device__ inline void gld16(const u16* g, u16* l) {
    __builtin_amdgcn_global_load_lds(
        (const __attribute__((address_space(1))) void*)g,
        (__attribute__((address_space(3))) void*)l, 16, 0, 0);
}

// ---------------------------------------------------------------------------
// one-shot: convert X + weights to bf16 (8 elems/thread), build decW^T,
// gather embeddings, zero c and h0.
// ---------------------------------------------------------------------------
__global__ void k_convert(const float* __restrict__ enc, const float* __restrict__ enc_W,
                          const float* __restrict__ dec_W, const float* __restrict__ W_ih,
                          const float* __restrict__ W_hh, const float* __restrict__ fc_W,
                          const float* __restrict__ emb, const int* __restrict__ caps,
                          u16* __restrict__ Xbf, u16* __restrict__ Wencbf,
                          u16* __restrict__ decWT, u16* __restrict__ Wihbf,
                          u16* __restrict__ Whhbf, u16* __restrict__ fcWbf,
                          u16* __restrict__ embg, float* __restrict__ cbuf,
                          u16* __restrict__ hb0) {
    long g = (long)blockIdx.x * 256 + threadIdx.x;   // 8-element groups
    if (g < 1605632) { cvt8(enc + g * 8, Xbf + g * 8); return; }
    g -= 1605632;
    if (g < 131072) { cvt8(enc_W + g * 8, Wencbf + g * 8); return; }
    g -= 131072;
    if (g < 32768) {   // decWT[k][a] = dec_W[a][k]
        int a = (int)(g >> 6), k8 = (int)(g & 63) * 8;
        float4 v0 = *(const float4*)(dec_W + (size_t)a * 512 + k8);
        float4 v1 = *(const float4*)(dec_W + (size_t)a * 512 + k8 + 4);
        decWT[(size_t)(k8 + 0) * 512 + a] = f2bf(v0.x);
        decWT[(size_t)(k8 + 1) * 512 + a] = f2bf(v0.y);
        decWT[(size_t)(k8 + 2) * 512 + a] = f2bf(v0.z);
        decWT[(size_t)(k8 + 3) * 512 + a] = f2bf(v0.w);
        decWT[(size_t)(k8 + 4) * 512 + a] = f2bf(v1.x);
        decWT[(size_t)(k8 + 5) * 512 + a] = f2bf(v1.y);
        decWT[(size_t)(k8 + 6) * 512 + a] = f2bf(v1.z);
        decWT[(size_t)(k8 + 7) * 512 + a] = f2bf(v1.w);
        return;
    }
    g -= 32768;
    if (g < 655360) { cvt8(W_ih + g * 8, Wihbf + g * 8); return; }
    g -= 655360;
    if (g < 131072) { cvt8(W_hh + g * 8, Whhbf + g * 8); return; }
    g -= 131072;
    if (g < 640000) { cvt8(fc_W + g * 8, fcWbf + g * 8); return; }
    g -= 640000;
    if (g < 40960) {   // emb gather: embg[b][t][512]
        long w = g >> 6, e8 = (g & 63) * 8;
        long b = w / 20, t = w - b * 20;
        int tok = caps[b * 21 + t];
        cvt8(emb + (size_t)tok * 512 + e8, embg + (size_t)w * 512 + e8);
        return;
    }
    g -= 40960;
    if (g < 2048) {
        *(float4*)(cbuf + g * 8) = make_float4(0.f, 0.f, 0.f, 0.f);
        *(float4*)(cbuf + g * 8 + 4) = make_float4(0.f, 0.f, 0.f, 0.f);
        return;
    }
    g -= 2048;
    if (g < 2048) { u16x8 z = {}; *(u16x8*)(hb0 + g * 8) = z; }
}

// ---------------------------------------------------------------------------
// enc_proj = X(6272x2048) @ enc_W^T(2048x512) + enc_b, bf16 MFMA, f32 out.
// BM=64 x BN=128 tile, 4 waves x (32r x 64c), BK=32, double-buffered LDS,
// global_load_lds width-16 staging, K-split x2 (grid z). Grid (98,4,2).
// kz=0 -> encproj (with bias); kz=1 -> scratch (= logits out buffer).
// ---------------------------------------------------------------------------
__global__ __launch_bounds__(256) void k_encproj(const u16* __restrict__ Xbf,
                                                 const u16* __restrict__ Wencbf,
                                                 const float* __restrict__ enc_b,
                                                 float* __restrict__ encproj,
                                                 float* __restrict__ scratch) {
    __shared__ u16 As[2][64 * 32];    // 4 KB per buf
    __shared__ u16 Bs[2][128 * 32];   // 8 KB per buf
    int tid = threadIdx.x, lane = tid & 63, w = tid >> 6;
    int wr = w >> 1, wc = w & 1;                 // wave -> 32x64 sub-tile
    int i0 = blockIdx.x * 64, j0 = blockIdx.y * 128;
    int kbase = blockIdx.z * 1024;               // K-split 0..1
    int ar = lane & 15, kg = lane >> 4;          // fragment row / k-group

    int srow = tid >> 2;                 // 0..63
    int sc = (tid & 3) * 8;              // u16 col within 32
    const u16* gA  = Xbf + (size_t)(i0 + srow) * NE + kbase + sc;
    const u16* gB0 = Wencbf + (size_t)(j0 + srow) * NE + kbase + sc;
    const u16* gB1 = Wencbf + (size_t)(j0 + 64 + srow) * NE + kbase + sc;

    f32x4 acc[2][4] = {};

#define STAGE_EP(buf, k0)                                   \
    do {                                                    \
        gld16(gA + (k0), &As[buf][tid * 8]);                \
        gld16(gB0 + (k0), &Bs[buf][tid * 8]);               \
        gld16(gB1 + (k0), &Bs[buf][2048 + tid * 8]);        \
    } while (0)

    STAGE_EP(0, 0);
    __syncthreads();
    for (int ks = 0; ks < 32; ++ks) {
        int cur = ks & 1;
        if (ks < 31) STAGE_EP(cur ^ 1, (ks + 1) * 32);
        bf8 a[2], b[4];
#pragma unroll
        for (int m = 0; m < 2; ++m)
            a[m] = *(const bf8*)(&As[cur][(wr * 32 + m * 16 + ar) * 32 + kg * 8]);
#pragma unroll
        for (int n = 0; n < 4; ++n)
            b[n] = *(const bf8*)(&Bs[cur][(wc * 64 + n * 16 + ar) * 32 + kg * 8]);
#pragma unroll
        for (int m = 0; m < 2; ++m)
#pragma unroll
            for (int n = 0; n < 4; ++n)
                acc[m][n] = __builtin_amdgcn_mfma_f32_16x16x32_bf16(a[m], b[n], acc[m][n], 0, 0, 0);
        if (ks < 31) __syncthreads();
    }
#undef STAGE_EP

    float* dst = (blockIdx.z == 0) ? encproj : scratch;
    int rbase = kg * 4;
#pragma unroll
    for (int m = 0; m < 2; ++m) {
        int row = i0 + wr * 32 + m * 16 + rbase;
#pragma unroll
        for (int n = 0; n < 4; ++n) {
            int col = j0 + wc * 64 + n * 16 + ar;
            float bias = (blockIdx.z == 0) ? enc_b[col] : 0.f;
#pragma unroll
            for (int r = 0; r < 4; ++r)
                dst[(size_t)(row + r) * AA + col] = acc[m][n][r] + bias;
        }
    }
}

// ---------------------------------------------------------------------------
// reduce the enc_proj K-partial: encproj += scratch  (3,211,264 f32)
// ---------------------------------------------------------------------------
__global__ __launch_bounds__(256) void k_epred(float* __restrict__ encproj,
                                               const float* __restrict__ scratch) {
    long i = ((long)blockIdx.x * 256 + threadIdx.x) * 4;
    f32x4 v = *(const f32x4*)(encproj + i);
    v += *(const f32x4*)(scratch + i);
    *(f32x4*)(encproj + i) = v;
}

// ---------------------------------------------------------------------------
// FUSED attention: dec_proj + att + softmax + context, one block per b.
// 1024 thr (16 waves). All reductions block-local (round-4 atomic lesson).
// dec_proj via decWT (coalesced); att rows over waves; ctx cols over threads.
// No max-shift: |att| bounded (~3), softmax shift-invariant -> exact.
// ---------------------------------------------------------------------------
__global__ __launch_bounds__(1024) void k_attn(const u16* __restrict__ hcur,
                                               const u16* __restrict__ decWT,
                                               const float* __restrict__ dec_b,
                                               const float* __restrict__ encproj,
                                               const float* __restrict__ att_W,
                                               const float* __restrict__ att_b,
                                               const u16* __restrict__ Xbf,
                                               u16* __restrict__ ctxbf) {
    int b = blockIdx.x, tid = threadIdx.x;
    int lane = tid & 63, wv = tid >> 6;
    __shared__ float sh[512], saw[512], sdp2[2][512], sdp[512], sa[200];
    __shared__ float ssum;
    if (tid < 512) sh[tid] = bf2f(hcur[b * 512 + tid]);
    else           saw[tid - 512] = att_W[tid - 512];
    __syncthreads();
    // dec_proj: thread (j, half) sums 256 K-terms; decWT rows -> coalesced
    {
        int j = tid & 511, hf = tid >> 9;
        const u16* wp = decWT + (size_t)(hf * 256) * 512 + j;
        float acc = 0.f;
#pragma unroll 8
        for (int kk = 0; kk < 256; ++kk)
            acc += sh[hf * 256 + kk] * bf2f(wp[(size_t)kk * 512]);
        sdp2[hf][j] = acc;
    }
    __syncthreads();
    if (tid < 512) sdp[tid] = sdp2[0][tid] + sdp2[1][tid] + dec_b[tid];
    __syncthreads();
    float ab0 = att_b[0];
    for (int r = wv; r < NP; r += 16) {
        const f32x4* ep = (const f32x4*)(encproj + (size_t)(b * NP + r) * AA);
        f32x4 v0 = ep[lane * 2], v1 = ep[lane * 2 + 1];
        int a = lane * 8;
        float s = 0.f;
#pragma unroll
        for (int q = 0; q < 4; ++q) s += tanhf(v0[q] + sdp[a + q]) * saw[a + q];
#pragma unroll
        for (int q = 0; q < 4; ++q) s += tanhf(v1[q] + sdp[a + 4 + q]) * saw[a + 4 + q];
#pragma unroll
        for (int off = 32; off > 0; off >>= 1) s += __shfl_down(s, off, 64);
        if (lane == 0) sa[r] = expf(s + ab0);
    }
    __syncthreads();
    if (tid < 64) {
        float s = 0.f;
        for (int p = tid; p < NP; p += 64) s += sa[p];
#pragma unroll
        for (int off = 32; off > 0; off >>= 1) s += __shfl_down(s, off, 64);
        if (tid == 0) ssum = s;
    }
    __syncthreads();
    float inv = 1.f / ssum;
    const u16* xb = Xbf + (size_t)b * NP * NE + 2 * tid;
    float a0 = 0.f, a1 = 0.f;
#pragma unroll 4
    for (int p = 0; p < NP; ++p) {
        unsigned v = *(const unsigned*)(xb + (size_t)p * NE);
        float wgt = sa[p];
        a0 += wgt * bf2f((u16)(v & 0xffff));
        a1 += wgt * bf2f((u16)(v >> 16));
    }
    ushort2 o; o.x = f2bf(a0 * inv); o.y = f2bf(a1 * inv);
    *(ushort2*)(ctxbf + (size_t)b * NE + 2 * tid) = o;
}

// ---------------------------------------------------------------------------
// FUSED gates + LSTM cell. 16 blocks x 32 j-cols; wave w = gate w, all 32
// batch rows, full K=3072 (96 k-steps, direct-global loads). Gates exchanged
// via LDS; cell epilogue in-kernel (no gpart round-trip).
// h double-buffered across t (reads hcur, writes hnxt) -> no cross-block race.
// ---------------------------------------------------------------------------
__global__ __launch_bounds__(256) void k_gatecell(const u16* __restrict__ embg,
                                                  const u16* __restrict__ ctxbf,
                                                  const u16* __restrict__ hcur,
                                                  const u16* __restrict__ Wihbf,
                                                  const u16* __restrict__ Whhbf,
                                                  const float* __restrict__ b_ih,
                                                  const float* __restrict__ b_hh,
                                                  float* __restrict__ cbuf,
                                                  u16* __restrict__ hnxt,
                                                  u16* __restrict__ hallbf, int t) {
    int tid = threadIdx.x, lane = tid & 63, w = tid >> 6;
    int jb = blockIdx.x * 32;
    int ar = lane & 15, kg = lane >> 4, koff = kg * 8;
    __shared__ float sg[4][32][32];
    f32x4 acc[2][2] = {};
#pragma unroll 4
    for (int s = 0; s < 96; ++s) {
        int k0 = s * 32;
        int k = k0 + koff;
        const u16 *a0p, *a1p;
        if (k0 < 512) {
            a0p = embg + ((size_t)ar * 20 + t) * 512 + k;
            a1p = embg + ((size_t)(16 + ar) * 20 + t) * 512 + k;
        } else if (k0 < 2560) {
            a0p = ctxbf + (size_t)ar * NE + (k - 512);
            a1p = ctxbf + (size_t)(16 + ar) * NE + (k - 512);
        } else {
            a0p = hcur + (size_t)ar * HH + (k - 2560);
            a1p = hcur + (size_t)(16 + ar) * HH + (k - 2560);
        }
        bf8 a0 = *(const bf8*)a0p, a1 = *(const bf8*)a1p;
#pragma unroll
        for (int n = 0; n < 2; ++n) {
            int c = w * 512 + jb + n * 16 + ar;
            const u16* bp = (k0 < 2560) ? (Wihbf + (size_t)c * 2560 + k)
                                        : (Whhbf + (size_t)c * 512 + (k - 2560));
            bf8 bv = *(const bf8*)bp;
            acc[0][n] = __builtin_amdgcn_mfma_f32_16x16x32_bf16(a0, bv, acc[0][n], 0, 0, 0);
            acc[1][n] = __builtin_amdgcn_mfma_f32_16x16x32_bf16(a1, bv, acc[1][n], 0, 0, 0);
        }
    }
#pragma unroll
    for (int m = 0; m < 2; ++m)
#pragma unroll
        for (int n = 0; n < 2; ++n)
#pragma unroll
            for (int q = 0; q < 4; ++q)
                sg[w][m * 16 + kg * 4 + q][n * 16 + ar] = acc[m][n][q];
    __syncthreads();
#pragma unroll
    for (int u = 0; u < 4; ++u) {
        int pos = u * 256 + tid;
        int bb = pos >> 5, jl = pos & 31, j = jb + jl;
        float gi = sg[0][bb][jl] + b_ih[j] + b_hh[j];
        float gf = sg[1][bb][jl] + b_ih[512 + j] + b_hh[512 + j];
        float gg = sg[2][bb][jl] + b_ih[1024 + j] + b_hh[1024 + j];
        float go = sg[3][bb][jl] + b_ih[1536 + j] + b_hh[1536 + j];
        float si = 1.f / (1.f + expf(-gi));
        float sf = 1.f / (1.f + expf(-gf));
        float so = 1.f / (1.f + expf(-go));
        float c2 = sf * cbuf[bb * 512 + j] + si * tanhf(gg);
        cbuf[bb * 512 + j] = c2;
        u16 hb = f2bf(so * tanhf(c2));
        hnxt[bb * 512 + j] = hb;
        hallbf[(bb * 20 + t) * 512 + j] = hb;
    }
}

// ---------------------------------------------------------------------------
// logits (batched over all t): hall(640x512) @ fc_W^T(512x10000) + fc_b
// m97 structure: 128x128 tile, 4 waves x 64x64, BK=32, double-buffered LDS,
// global_load_lds width-16 staging. Grid (5, 79); B-rows clamped at NV,
// epilogue stores only col < NV.
// ---------------------------------------------------------------------------
__global__ __launch_bounds__(256) void k_logits(const u16* __restrict__ hallbf,
                                                const u16* __restrict__ fcWbf,
                                                const float* __restrict__ fc_b,
                                                float* __restrict__ out) {
    __shared__ u16 As[2][128 * 32];
    __shared__ u16 Bs[2][128 * 32];
    int tid = threadIdx.x, lane = tid & 63, w = tid >> 6;
    int wr = w >> 1, wc = w & 1;
    int i0 = blockIdx.x * 128, j0 = blockIdx.y * 128;
    int ar = lane & 15, kg = lane >> 4;

    int srow = tid >> 2;                 // 0..63
    int sc = (tid & 3) * 8;              // u16 col within 32
    int brow0 = min(j0 + srow, NV - 1);        // clamp: keep reads in-bounds
    int brow1 = min(j0 + 64 + srow, NV - 1);
    const u16* gA0 = hallbf + (size_t)(i0 + srow) * HH + sc;
    const u16* gA1 = hallbf + (size_t)(i0 + 64 + srow) * HH + sc;
    const u16* gB0 = fcWbf + (size_t)brow0 * HH + sc;
    const u16* gB1 = fcWbf + (size_t)brow1 * HH + sc;

    f32x4 acc[4][4] = {};

#define STAGE_LG(buf, k0)                                   \
    do {                                                    \
        gld16(gA0 + (k0), &As[buf][tid * 8]);               \
        gld16(gA1 + (k0), &As[buf][2048 + tid * 8]);        \
        gld16(gB0 + (k0), &Bs[buf][tid * 8]);               \
        gld16(gB1 + (k0), &Bs[buf][2048 + tid * 8]);        \
    } while (0)

    STAGE_LG(0, 0);
    __syncthreads();
    for (int ks = 0; ks < 16; ++ks) {
        int cur = ks & 1;
        if (ks < 15) STAGE_LG(cur ^ 1, (ks + 1) * 32);
        bf8 a[4], b[4];
#pragma unroll
        for (int m = 0; m < 4; ++m)
            a[m] = *(const bf8*)(&As[cur][(wr * 64 + m * 16 + ar) * 32 + kg * 8]);
#pragma unroll
        for (int n = 0; n < 4; ++n)
            b[n] = *(const bf8*)(&Bs[cur][(wc * 64 + n * 16 + ar) * 32 + kg * 8]);
#pragma unroll
        for (int m = 0; m < 4; ++m)
#pragma unroll
            for (int n = 0; n < 4; ++n)
                acc[m][n] = __builtin_amdgcn_mfma_f32_16x16x32_bf16(a[m], b[n], acc[m][n], 0, 0, 0);
        if (ks < 15) __syncthreads();
    }
#undef STAGE_LG

    int rbase = kg * 4;
#pragma unroll
    for (int m = 0; m < 4; ++m) {
        int row = i0 + wr * 64 + m * 16 + rbase;
#pragma unroll
        for (int n = 0; n < 4; ++n) {
            int col = j0 + wc * 64 + n * 16 + ar;
            if (col < NV) {
                float bias = fc_b[col];
#pragma unroll
                for (int r = 0; r < 4; ++r)
                    out[(size_t)(row + r) * NV + col] = acc[m][n][r] + bias;
            }
        }
    }
}

// ---------------------------------------------------------------------------
extern "C" void kernel_launch(void* const* d_in, const int* in_sizes, int n_in,
                              void* d_out, int out_size, void* d_ws, size_t ws_size,
                              hipStream_t stream) {
    (void)in_sizes; (void)n_in; (void)out_size; (void)ws_size;
    const float* enc   = (const float*)d_in[0];
    const int*   caps  = (const int*)d_in[1];
    const float* emb   = (const float*)d_in[2];
    const float* enc_W = (const float*)d_in[3];
    const float* enc_b = (const float*)d_in[4];
    const float* dec_W = (const float*)d_in[5];
    const float* dec_b = (const float*)d_in[6];
    const float* att_W = (const float*)d_in[7];
    const float* att_b = (const float*)d_in[8];
    const float* W_ih  = (const float*)d_in[9];
    const float* W_hh  = (const float*)d_in[10];
    const float* b_ih  = (const float*)d_in[11];
    const float* b_hh  = (const float*)d_in[12];
    const float* fc_W  = (const float*)d_in[13];
    const float* fc_b  = (const float*)d_in[14];
    float* out = (float*)d_out;

    char* base = (char*)d_ws;
    float* encproj = (float*)base;                 base += (size_t)6272 * 512 * 4;
    float* cbuf    = (float*)base;                 base += (size_t)32 * 512 * 4;
    u16* Xbf    = (u16*)base;                      base += (size_t)32 * 196 * 2048 * 2;
    u16* Wencbf = (u16*)base;                      base += (size_t)512 * 2048 * 2;
    u16* decWT  = (u16*)base;                      base += (size_t)512 * 512 * 2;
    u16* Wihbf  = (u16*)base;                      base += (size_t)2048 * 2560 * 2;
    u16* Whhbf  = (u16*)base;                      base += (size_t)2048 * 512 * 2;
    u16* fcWbf  = (u16*)base;                      base += (size_t)10000 * 512 * 2;
    u16* embg   = (u16*)base;                      base += (size_t)32 * 20 * 512 * 2;
    u16* ctxbf  = (u16*)base;                      base += (size_t)32 * 2048 * 2;
    u16* hbuf   = (u16*)base;                      base += (size_t)2 * 32 * 512 * 2;
    u16* hallbf = (u16*)base;                      base += (size_t)32 * 20 * 512 * 2;
    u16* hb0 = hbuf;
    u16* hb1 = hbuf + 32 * 512;

    k_convert<<<12660, 256, 0, stream>>>(enc, enc_W, dec_W, W_ih, W_hh, fc_W, emb, caps,
                                         Xbf, Wencbf, decWT, Wihbf, Whhbf, fcWbf,
                                         embg, cbuf, hb0);
    k_encproj<<<dim3(98, 4, 2), 256, 0, stream>>>(Xbf, Wencbf, enc_b, encproj, out);
    k_epred<<<3136, 256, 0, stream>>>(encproj, out);
    for (int t = 0; t < NT; ++t) {
        u16* hcur = (t & 1) ? hb1 : hb0;
        u16* hnxt = (t & 1) ? hb0 : hb1;
        k_attn<<<32, 1024, 0, stream>>>(hcur, decWT, dec_b, encproj, att_W, att_b,
                                        Xbf, ctxbf);
        k_gatecell<<<16, 256, 0, stream>>>(embg, ctxbf, hcur, Wihbf, Whhbf,
                                           b_ih, b_hh, cbuf, hnxt, hallbf, t);
    }
    k_logits<<<dim3(5, 79), 256, 0, stream>>>(hallbf, fcWbf, fc_b, out);
}

// Round 7
// 794.434 us; speedup vs baseline: 2.9545x; 2.9545x over previous
//
#include <hip/hip_runtime.h>
#include <math.h>

typedef unsigned short u16;
typedef __attribute__((ext_vector_type(8))) short bf8;    // 8 bf16 in 4 VGPRs
typedef __attribute__((ext_vector_type(8))) unsigned short u16x8;
typedef __attribute__((ext_vector_type(4))) float f32x4;

constexpr int NB = 32;      // batch
constexpr int NP = 196;     // pixels
constexpr int NE = 2048;    // encoder dim
constexpr int ED = 512;     // embedding dim
constexpr int HH = 512;     // hidden
constexpr int AA = 512;     // attention dim
constexpr int NV = 10000;   // vocab
constexpr int NT = 20;      // timesteps

__device__ inline u16 f2bf(float f) {
    unsigned u = __builtin_bit_cast(unsigned, f);
    u += 0x7fffu + ((u >> 16) & 1u);          // RNE
    return (u16)(u >> 16);
}
__device__ inline float bf2f(u16 h) {
    return __builtin_bit_cast(float, (unsigned)h << 16);
}
__device__ inline void cvt8(const float* __restrict__ s, u16* __restrict__ d) {
    float4 v0 = *(const float4*)s, v1 = *(const float4*)(s + 4);
    u16x8 o;
    o[0] = f2bf(v0.x); o[1] = f2bf(v0.y); o[2] = f2bf(v0.z); o[3] = f2bf(v0.w);
    o[4] = f2bf(v1.x); o[5] = f2bf(v1.y); o[6] = f2bf(v1.z); o[7] = f2bf(v1.w);
    *(u16x8*)d = o;
}

// async global->LDS, 16 bytes per lane (global_load_lds_dwordx4)
__device__ inline void gld16(const u16* g, u16* l) {
    __builtin_amdgcn_global_load_lds(
        (const __attribute__((address_space(1))) void*)g,
        (__attribute__((address_space(3))) void*)l, 16, 0, 0);
}

// ---------------------------------------------------------------------------
// one-shot: convert X + all weights to bf16 (8 elems/thread), gather
// embeddings, zero c and h.
// ---------------------------------------------------------------------------
__global__ void k_convert(const float* __restrict__ enc, const float* __restrict__ enc_W,
                          const float* __restrict__ dec_W, const float* __restrict__ W_ih,
                          const float* __restrict__ W_hh, const float* __restrict__ fc_W,
                          const float* __restrict__ emb, const int* __restrict__ caps,
                          u16* __restrict__ Xbf, u16* __restrict__ Wencbf,
                          u16* __restrict__ decWbf, u16* __restrict__ Wihbf,
                          u16* __restrict__ Whhbf, u16* __restrict__ fcWbf,
                          u16* __restrict__ embg, float* __restrict__ cbuf,
                          u16* __restrict__ hbf) {
    long g = (long)blockIdx.x * 256 + threadIdx.x;   // 8-element groups
    if (g < 1605632) { cvt8(enc + g * 8, Xbf + g * 8); return; }
    g -= 1605632;
    if (g < 131072) { cvt8(enc_W + g * 8, Wencbf + g * 8); return; }
    g -= 131072;
    if (g < 32768) { cvt8(dec_W + g * 8, decWbf + g * 8); return; }
    g -= 32768;
    if (g < 655360) { cvt8(W_ih + g * 8, Wihbf + g * 8); return; }
    g -= 655360;
    if (g < 131072) { cvt8(W_hh + g * 8, Whhbf + g * 8); return; }
    g -= 131072;
    if (g < 640000) { cvt8(fc_W + g * 8, fcWbf + g * 8); return; }
    g -= 640000;
    if (g < 40960) {   // emb gather: embg[b][t][512]
        long w = g >> 6, e8 = (g & 63) * 8;
        long b = w / 20, t = w - b * 20;
        int tok = caps[b * 21 + t];
        cvt8(emb + (size_t)tok * 512 + e8, embg + (size_t)w * 512 + e8);
        return;
    }
    g -= 40960;
    if (g < 2048) {
        *(float4*)(cbuf + g * 8) = make_float4(0.f, 0.f, 0.f, 0.f);
        *(float4*)(cbuf + g * 8 + 4) = make_float4(0.f, 0.f, 0.f, 0.f);
        return;
    }
    g -= 2048;
    if (g < 2048) { u16x8 z = {}; *(u16x8*)(hbf + g * 8) = z; }
}

// ---------------------------------------------------------------------------
// enc_proj = X(6272x2048) @ enc_W^T(2048x512) + enc_b, bf16 MFMA, f32 out.
// BM=64 x BN=128 tile, 4 waves x (32r x 64c), BK=32, double-buffered LDS,
// global_load_lds width-16 staging, K-split x2 (grid z). Grid (98,4,2).
// kz=0 -> encproj (with bias); kz=1 -> scratch (= logits out buffer).
// ---------------------------------------------------------------------------
__global__ __launch_bounds__(256) void k_encproj(const u16* __restrict__ Xbf,
                                                 const u16* __restrict__ Wencbf,
                                                 const float* __restrict__ enc_b,
                                                 float* __restrict__ encproj,
                                                 float* __restrict__ scratch) {
    __shared__ u16 As[2][64 * 32];    // 4 KB per buf
    __shared__ u16 Bs[2][128 * 32];   // 8 KB per buf
    int tid = threadIdx.x, lane = tid & 63, w = tid >> 6;
    int wr = w >> 1, wc = w & 1;                 // wave -> 32x64 sub-tile
    int i0 = blockIdx.x * 64, j0 = blockIdx.y * 128;
    int kbase = blockIdx.z * 1024;               // K-split 0..1
    int ar = lane & 15, kg = lane >> 4;          // fragment row / k-group

    int srow = tid >> 2;                 // 0..63
    int sc = (tid & 3) * 8;              // u16 col within 32
    const u16* gA  = Xbf + (size_t)(i0 + srow) * NE + kbase + sc;
    const u16* gB0 = Wencbf + (size_t)(j0 + srow) * NE + kbase + sc;
    const u16* gB1 = Wencbf + (size_t)(j0 + 64 + srow) * NE + kbase + sc;

    f32x4 acc[2][4] = {};

#define STAGE_EP(buf, k0)                                   \
    do {                                                    \
        gld16(gA + (k0), &As[buf][tid * 8]);                \
        gld16(gB0 + (k0), &Bs[buf][tid * 8]);               \
        gld16(gB1 + (k0), &Bs[buf][2048 + tid * 8]);        \
    } while (0)

    STAGE_EP(0, 0);
    __syncthreads();
    for (int ks = 0; ks < 32; ++ks) {
        int cur = ks & 1;
        if (ks < 31) STAGE_EP(cur ^ 1, (ks + 1) * 32);
        bf8 a[2], b[4];
#pragma unroll
        for (int m = 0; m < 2; ++m)
            a[m] = *(const bf8*)(&As[cur][(wr * 32 + m * 16 + ar) * 32 + kg * 8]);
#pragma unroll
        for (int n = 0; n < 4; ++n)
            b[n] = *(const bf8*)(&Bs[cur][(wc * 64 + n * 16 + ar) * 32 + kg * 8]);
#pragma unroll
        for (int m = 0; m < 2; ++m)
#pragma unroll
            for (int n = 0; n < 4; ++n)
                acc[m][n] = __builtin_amdgcn_mfma_f32_16x16x32_bf16(a[m], b[n], acc[m][n], 0, 0, 0);
        if (ks < 31) __syncthreads();
    }
#undef STAGE_EP

    float* dst = (blockIdx.z == 0) ? encproj : scratch;
    int rbase = kg * 4;
#pragma unroll
    for (int m = 0; m < 2; ++m) {
        int row = i0 + wr * 32 + m * 16 + rbase;
#pragma unroll
        for (int n = 0; n < 4; ++n) {
            int col = j0 + wc * 64 + n * 16 + ar;
            float bias = (blockIdx.z == 0) ? enc_b[col] : 0.f;
#pragma unroll
            for (int r = 0; r < 4; ++r)
                dst[(size_t)(row + r) * AA + col] = acc[m][n][r] + bias;
        }
    }
}

// ---------------------------------------------------------------------------
// reduce the enc_proj K-partial: encproj += scratch  (3,211,264 f32)
// ---------------------------------------------------------------------------
__global__ __launch_bounds__(256) void k_epred(float* __restrict__ encproj,
                                               const float* __restrict__ scratch) {
    long i = ((long)blockIdx.x * 256 + threadIdx.x) * 4;
    f32x4 v = *(const f32x4*)(encproj + i);
    v += *(const f32x4*)(scratch + i);
    *(f32x4*)(encproj + i) = v;
}

// ---------------------------------------------------------------------------
// dec_proj partials: h(32x512) @ dec_W^T -> dpart[4][32][512] (k-split 4)
// 16 blocks x 4 waves; wave = (ks, rg, cg): 16 rows x 64 cols, K-chunk 128
// ---------------------------------------------------------------------------
__global__ __launch_bounds__(256) void k_decproj(const u16* __restrict__ hbf,
                                                 const u16* __restrict__ decWbf,
                                                 float* __restrict__ dpart) {
    int tid = threadIdx.x, lane = tid & 63;
    int ww = blockIdx.x * 4 + (tid >> 6);
    int ks = ww >> 4, rem = ww & 15, rg = rem >> 3, cg = rem & 7;
    int ar = lane & 15, koff = (lane >> 4) * 8;
    const u16* Arow = hbf + (rg * 16 + ar) * HH + koff + ks * 128;
    f32x4 acc[4] = {};
#pragma unroll
    for (int s = 0; s < 4; ++s) {
        int k0 = s * 32;
        bf8 a = *(const bf8*)(Arow + k0);
#pragma unroll
        for (int jt = 0; jt < 4; ++jt) {
            bf8 b = *(const bf8*)(decWbf + (cg * 64 + jt * 16 + ar) * HH + ks * 128 + k0 + koff);
            acc[jt] = __builtin_amdgcn_mfma_f32_16x16x32_bf16(a, b, acc[jt], 0, 0, 0);
        }
    }
    int bb = rg * 16 + (lane >> 4) * 4;
#pragma unroll
    for (int jt = 0; jt < 4; ++jt) {
        int col = cg * 64 + jt * 16 + ar;
#pragma unroll
        for (int r = 0; r < 4; ++r)
            dpart[(ks * NB + bb + r) * AA + col] = acc[jt][r];
    }
}

// ---------------------------------------------------------------------------
// attexp[b,p] = exp(att_b + sum_a att_W[a]*tanh(enc_proj[b,p,a]+dec_proj[b,a]))
// No atomic (round-4 lesson); denominator computed locally in k_ctx.
// No max-shift: |att| bounded (~3), softmax shift-invariant -> exact.
// ---------------------------------------------------------------------------
__global__ __launch_bounds__(256) void k_attexp(const float* __restrict__ encproj,
                                                const float* __restrict__ dpart,
                                                const float* __restrict__ dec_b,
                                                const float* __restrict__ att_W,
                                                const float* __restrict__ att_b,
                                                float* __restrict__ attb) {
    int tid = threadIdx.x, lane = tid & 63;
    int row = blockIdx.x * 4 + (tid >> 6);
    int b = row / NP;
    const f32x4* ep = (const f32x4*)(encproj + (size_t)row * AA);
    const f32x4* d0 = (const f32x4*)(dpart + b * AA);
    const f32x4* d1 = (const f32x4*)(dpart + (NB + b) * AA);
    const f32x4* d2 = (const f32x4*)(dpart + (2 * NB + b) * AA);
    const f32x4* d3 = (const f32x4*)(dpart + (3 * NB + b) * AA);
    const f32x4* db = (const f32x4*)dec_b;
    const f32x4* aw = (const f32x4*)att_W;
    float s = 0.f;
#pragma unroll
    for (int h = 0; h < 2; ++h) {
        int ix = h * 64 + lane;
        f32x4 x = ep[ix];
        f32x4 d = d0[ix] + d1[ix] + d2[ix] + d3[ix] + db[ix];
        f32x4 wv = aw[ix];
        s += tanhf(x[0] + d[0]) * wv[0] + tanhf(x[1] + d[1]) * wv[1] +
             tanhf(x[2] + d[2]) * wv[2] + tanhf(x[3] + d[3]) * wv[3];
    }
#pragma unroll
    for (int off = 32; off > 0; off >>= 1) s += __shfl_down(s, off, 64);
    if (lane == 0) attb[row] = expf(s + att_b[0]);
}

// ---------------------------------------------------------------------------
// context from exp'd weights: ctx[b,:] = (sum_p attb[b,p]*X[b,p,:]) / sum_p
// grid (32 b x 16 chunks) x 512 thr; local denominator reduce, LDS reduce.
// ---------------------------------------------------------------------------
__global__ __launch_bounds__(512) void k_ctx(const float* __restrict__ attb,
                                             const u16* __restrict__ Xbf,
                                             u16* __restrict__ ctxbf) {
    int b = blockIdx.x >> 4, chunk = blockIdx.x & 15;
    int tid = threadIdx.x;
    __shared__ float sa[NP];
    __shared__ float sred[4][128];
    __shared__ float ssum;
    if (tid < NP) sa[tid] = attb[b * NP + tid];
    __syncthreads();
    if (tid < 64) {
        float s = 0.f;
        for (int p = tid; p < NP; p += 64) s += sa[p];
#pragma unroll
        for (int off = 32; off > 0; off >>= 1) s += __shfl_down(s, off, 64);
        if (tid == 0) ssum = s;
    }
    __syncthreads();
    float inv = 1.f / ssum;
    int col_l = tid & 127, pg = tid >> 7;
    int col = chunk * 128 + col_l;
    const u16* e = Xbf + (size_t)b * NP * NE + (size_t)pg * 49 * NE + col;
    float acc = 0.f;
#pragma unroll 7
    for (int p = 0; p < 49; ++p) acc += sa[pg * 49 + p] * bf2f(e[(size_t)p * NE]);
    sred[pg][col_l] = acc;
    __syncthreads();
    if (tid < 128) {
        float v = (sred[0][tid] + sred[1][tid] + sred[2][tid] + sred[3][tid]) * inv;
        ctxbf[b * NE + chunk * 128 + tid] = f2bf(v);
    }
}

// ---------------------------------------------------------------------------
// gates partials: [emb|ctx|h](32x3072) @ [W_ih;W_hh]^T -> gpart[8][32][2048]
// 128 blocks x 4 waves; wave = (ks 0..7, rg 0..1, cg 0..31): 16r x 64c, K 384
// ---------------------------------------------------------------------------
__global__ __launch_bounds__(256) void k_gates(const u16* __restrict__ embg,
                                               const u16* __restrict__ ctxbf,
                                               const u16* __restrict__ hbf,
                                               const u16* __restrict__ Wihbf,
                                               const u16* __restrict__ Whhbf,
                                               float* __restrict__ gpart, int t) {
    int tid = threadIdx.x, lane = tid & 63;
    int ww = blockIdx.x * 4 + (tid >> 6);
    int cg = ww & 31, rg = (ww >> 5) & 1, ks = ww >> 6;
    int ar = lane & 15, koff = (lane >> 4) * 8;
    int arow = rg * 16 + ar;
    f32x4 acc[4] = {};
#pragma unroll
    for (int s = 0; s < 12; ++s) {
        int k0 = ks * 384 + s * 32;
        int k = k0 + koff;
        const u16* aptr;
        if (k0 < 512)        aptr = embg + ((size_t)arow * 20 + t) * 512 + k;
        else if (k0 < 2560)  aptr = ctxbf + (size_t)arow * NE + (k - 512);
        else                 aptr = hbf + (size_t)arow * HH + (k - 2560);
        bf8 a = *(const bf8*)aptr;
#pragma unroll
        for (int jt = 0; jt < 4; ++jt) {
            int c = cg * 64 + jt * 16 + ar;
            const u16* bptr = (k0 < 2560) ? (Wihbf + (size_t)c * 2560 + k)
                                          : (Whhbf + (size_t)c * 512 + (k - 2560));
            bf8 bfr = *(const bf8*)bptr;
            acc[jt] = __builtin_amdgcn_mfma_f32_16x16x32_bf16(a, bfr, acc[jt], 0, 0, 0);
        }
    }
    int bb = rg * 16 + (lane >> 4) * 4;
#pragma unroll
    for (int jt = 0; jt < 4; ++jt) {
        int col = cg * 64 + jt * 16 + ar;
#pragma unroll
        for (int r = 0; r < 4; ++r)
            gpart[(size_t)(ks * NB + bb + r) * 2048 + col] = acc[jt][r];
    }
}

// ---------------------------------------------------------------------------
// LSTM cell: sum 8 partials, biases, update c; h -> hbf (current) + hallbf[t]
// ---------------------------------------------------------------------------
__global__ void k_cell(const float* __restrict__ gpart, const float* __restrict__ b_ih,
                       const float* __restrict__ b_hh, float* __restrict__ cbuf,
                       u16* __restrict__ hbf, u16* __restrict__ hallbf, int t) {
    int idx = blockIdx.x * 256 + threadIdx.x;   // 16384
    int b = idx >> 9, j = idx & 511;
    float g4[4];
#pragma unroll
    for (int q = 0; q < 4; ++q) {
        int col = j + q * 512;
        float s = b_ih[col] + b_hh[col];
#pragma unroll
        for (int ks = 0; ks < 8; ++ks) s += gpart[(size_t)(ks * NB + b) * 2048 + col];
        g4[q] = s;
    }
    float si = 1.f / (1.f + expf(-g4[0]));
    float sf = 1.f / (1.f + expf(-g4[1]));
    float so = 1.f / (1.f + expf(-g4[3]));
    float c2 = sf * cbuf[idx] + si * tanhf(g4[2]);
    cbuf[idx] = c2;
    u16 hb = f2bf(so * tanhf(c2));
    hbf[b * 512 + j] = hb;
    hallbf[(b * 20 + t) * 512 + j] = hb;
}

// ---------------------------------------------------------------------------
// logits (batched over all t): hall(640x512) @ fc_W^T(512x10000) + fc_b
// m97 structure: 128x128 tile, 4 waves x 64x64, BK=32, double-buffered LDS,
// global_load_lds width-16 staging. Grid (5, 79); B-rows clamped at NV,
// epilogue stores only col < NV.
// ---------------------------------------------------------------------------
__global__ __launch_bounds__(256) void k_logits(const u16* __restrict__ hallbf,
                                                const u16* __restrict__ fcWbf,
                                                const float* __restrict__ fc_b,
                                                float* __restrict__ out) {
    __shared__ u16 As[2][128 * 32];
    __shared__ u16 Bs[2][128 * 32];
    int tid = threadIdx.x, lane = tid & 63, w = tid >> 6;
    int wr = w >> 1, wc = w & 1;
    int i0 = blockIdx.x * 128, j0 = blockIdx.y * 128;
    int ar = lane & 15, kg = lane >> 4;

    int srow = tid >> 2;                 // 0..63
    int sc = (tid & 3) * 8;              // u16 col within 32
    int brow0 = min(j0 + srow, NV - 1);        // clamp: keep reads in-bounds
    int brow1 = min(j0 + 64 + srow, NV - 1);
    const u16* gA0 = hallbf + (size_t)(i0 + srow) * HH + sc;
    const u16* gA1 = hallbf + (size_t)(i0 + 64 + srow) * HH + sc;
    const u16* gB0 = fcWbf + (size_t)brow0 * HH + sc;
    const u16* gB1 = fcWbf + (size_t)brow1 * HH + sc;

    f32x4 acc[4][4] = {};

#define STAGE_LG(buf, k0)                                   \
    do {                                                    \
        gld16(gA0 + (k0), &As[buf][tid * 8]);               \
        gld16(gA1 + (k0), &As[buf][2048 + tid * 8]);        \
        gld16(gB0 + (k0), &Bs[buf][tid * 8]);               \
        gld16(gB1 + (k0), &Bs[buf][2048 + tid * 8]);        \
    } while (0)

    STAGE_LG(0, 0);
    __syncthreads();
    for (int ks = 0; ks < 16; ++ks) {
        int cur = ks & 1;
        if (ks < 15) STAGE_LG(cur ^ 1, (ks + 1) * 32);
        bf8 a[4], b[4];
#pragma unroll
        for (int m = 0; m < 4; ++m)
            a[m] = *(const bf8*)(&As[cur][(wr * 64 + m * 16 + ar) * 32 + kg * 8]);
#pragma unroll
        for (int n = 0; n < 4; ++n)
            b[n] = *(const bf8*)(&Bs[cur][(wc * 64 + n * 16 + ar) * 32 + kg * 8]);
#pragma unroll
        for (int m = 0; m < 4; ++m)
#pragma unroll
            for (int n = 0; n < 4; ++n)
                acc[m][n] = __builtin_amdgcn_mfma_f32_16x16x32_bf16(a[m], b[n], acc[m][n], 0, 0, 0);
        if (ks < 15) __syncthreads();
    }
#undef STAGE_LG

    int rbase = kg * 4;
#pragma unroll
    for (int m = 0; m < 4; ++m) {
        int row = i0 + wr * 64 + m * 16 + rbase;
#pragma unroll
        for (int n = 0; n < 4; ++n) {
            int col = j0 + wc * 64 + n * 16 + ar;
            if (col < NV) {
                float bias = fc_b[col];
#pragma unroll
                for (int r = 0; r < 4; ++r)
                    out[(size_t)(row + r) * NV + col] = acc[m][n][r] + bias;
            }
        }
    }
}

// ---------------------------------------------------------------------------
extern "C" void kernel_launch(void* const* d_in, const int* in_sizes, int n_in,
                              void* d_out, int out_size, void* d_ws, size_t ws_size,
                              hipStream_t stream) {
    (void)in_sizes; (void)n_in; (void)out_size; (void)ws_size;
    const float* enc   = (const float*)d_in[0];
    const int*   caps  = (const int*)d_in[1];
    const float* emb   = (const float*)d_in[2];
    const float* enc_W = (const float*)d_in[3];
    const float* enc_b = (const float*)d_in[4];
    const float* dec_W = (const float*)d_in[5];
    const float* dec_b = (const float*)d_in[6];
    const float* att_W = (const float*)d_in[7];
    const float* att_b = (const float*)d_in[8];
    const float* W_ih  = (const float*)d_in[9];
    const float* W_hh  = (const float*)d_in[10];
    const float* b_ih  = (const float*)d_in[11];
    const float* b_hh  = (const float*)d_in[12];
    const float* fc_W  = (const float*)d_in[13];
    const float* fc_b  = (const float*)d_in[14];
    float* out = (float*)d_out;

    char* base = (char*)d_ws;
    float* encproj = (float*)base;                 base += (size_t)6272 * 512 * 4;
    float* dpart   = (float*)base;                 base += (size_t)4 * 32 * 512 * 4;
    float* attb    = (float*)base;                 base += (size_t)6272 * 4;
    float* cbuf    = (float*)base;                 base += (size_t)32 * 512 * 4;
    float* gpart   = (float*)base;                 base += (size_t)8 * 32 * 2048 * 4;
    u16* Xbf    = (u16*)base;                      base += (size_t)32 * 196 * 2048 * 2;
    u16* Wencbf = (u16*)base;                      base += (size_t)512 * 2048 * 2;
    u16* decWbf = (u16*)base;                      base += (size_t)512 * 512 * 2;
    u16* Wihbf  = (u16*)base;                      base += (size_t)2048 * 2560 * 2;
    u16* Whhbf  = (u16*)base;                      base += (size_t)2048 * 512 * 2;
    u16* fcWbf  = (u16*)base;                      base += (size_t)10000 * 512 * 2;
    u16* embg   = (u16*)base;                      base += (size_t)32 * 20 * 512 * 2;
    u16* ctxbf  = (u16*)base;                      base += (size_t)32 * 2048 * 2;
    u16* hbf    = (u16*)base;                      base += (size_t)32 * 512 * 2;
    u16* hallbf = (u16*)base;                      base += (size_t)32 * 20 * 512 * 2;

    k_convert<<<12660, 256, 0, stream>>>(enc, enc_W, dec_W, W_ih, W_hh, fc_W, emb, caps,
                                         Xbf, Wencbf, decWbf, Wihbf, Whhbf, fcWbf,
                                         embg, cbuf, hbf);
    k_encproj<<<dim3(98, 4, 2), 256, 0, stream>>>(Xbf, Wencbf, enc_b, encproj, out);
    k_epred<<<3136, 256, 0, stream>>>(encproj, out);
    for (int t = 0; t < NT; ++t) {
        k_decproj<<<16, 256, 0, stream>>>(hbf, decWbf, dpart);
        k_attexp<<<1568, 256, 0, stream>>>(encproj, dpart, dec_b, att_W, att_b, attb);
        k_ctx<<<512, 512, 0, stream>>>(attb, Xbf, ctxbf);
        k_gates<<<128, 256, 0, stream>>>(embg, ctxbf, hbf, Wihbf, Whhbf, gpart, t);
        k_cell<<<64, 256, 0, stream>>>(gpart, b_ih, b_hh, cbuf, hbf, hallbf, t);
    }
    k_logits<<<dim3(5, 79), 256, 0, stream>>>(hallbf, fcWbf, fc_b, out);
}

// Round 8
// 572.013 us; speedup vs baseline: 4.1034x; 1.3888x over previous
//
#include <hip/hip_runtime.h>
#include <math.h>

typedef unsigned short u16;
typedef __attribute__((ext_vector_type(8))) short bf8;    // 8 bf16 in 4 VGPRs
typedef __attribute__((ext_vector_type(8))) unsigned short u16x8;
typedef __attribute__((ext_vector_type(4))) float f32x4;

constexpr int NB = 32;      // batch
constexpr int NP = 196;     // pixels
constexpr int NE = 2048;    // encoder dim
constexpr int ED = 512;     // embedding dim
constexpr int HH = 512;     // hidden
constexpr int AA = 512;     // attention dim
constexpr int NV = 10000;   // vocab
constexpr int NT = 20;      // timesteps

__device__ inline u16 f2bf(float f) {
    unsigned u = __builtin_bit_cast(unsigned, f);
    u += 0x7fffu + ((u >> 16) & 1u);          // RNE
    return (u16)(u >> 16);
}
__device__ inline float bf2f(u16 h) {
    return __builtin_bit_cast(float, (unsigned)h << 16);
}
__device__ inline void cvt8(const float* __restrict__ s, u16* __restrict__ d) {
    float4 v0 = *(const float4*)s, v1 = *(const float4*)(s + 4);
    u16x8 o;
    o[0] = f2bf(v0.x); o[1] = f2bf(v0.y); o[2] = f2bf(v0.z); o[3] = f2bf(v0.w);
    o[4] = f2bf(v1.x); o[5] = f2bf(v1.y); o[6] = f2bf(v1.z); o[7] = f2bf(v1.w);
    *(u16x8*)d = o;
}

// async global->LDS, 16 bytes per lane (global_load_lds_dwordx4)
__device__ inline void gld16(const u16* g, u16* l) {
    __builtin_amdgcn_global_load_lds(
        (const __attribute__((address_space(1))) void*)g,
        (__attribute__((address_space(3))) void*)l, 16, 0, 0);
}

// ---------------------------------------------------------------------------
// one-shot: convert X + all weights to bf16 (8 elems/thread), gather
// embeddings, zero c and h.
// ---------------------------------------------------------------------------
__global__ void k_convert(const float* __restrict__ enc, const float* __restrict__ enc_W,
                          const float* __restrict__ dec_W, const float* __restrict__ W_ih,
                          const float* __restrict__ W_hh, const float* __restrict__ fc_W,
                          const float* __restrict__ emb, const int* __restrict__ caps,
                          u16* __restrict__ Xbf, u16* __restrict__ Wencbf,
                          u16* __restrict__ decWbf, u16* __restrict__ Wihbf,
                          u16* __restrict__ Whhbf, u16* __restrict__ fcWbf,
                          u16* __restrict__ embg, float* __restrict__ cbuf,
                          u16* __restrict__ hbf) {
    long g = (long)blockIdx.x * 256 + threadIdx.x;   // 8-element groups
    if (g < 1605632) { cvt8(enc + g * 8, Xbf + g * 8); return; }
    g -= 1605632;
    if (g < 131072) { cvt8(enc_W + g * 8, Wencbf + g * 8); return; }
    g -= 131072;
    if (g < 32768) { cvt8(dec_W + g * 8, decWbf + g * 8); return; }
    g -= 32768;
    if (g < 655360) { cvt8(W_ih + g * 8, Wihbf + g * 8); return; }
    g -= 655360;
    if (g < 131072) { cvt8(W_hh + g * 8, Whhbf + g * 8); return; }
    g -= 131072;
    if (g < 640000) { cvt8(fc_W + g * 8, fcWbf + g * 8); return; }
    g -= 640000;
    if (g < 40960) {   // emb gather: embg[b][t][512]
        long w = g >> 6, e8 = (g & 63) * 8;
        long b = w / 20, t = w - b * 20;
        int tok = caps[b * 21 + t];
        cvt8(emb + (size_t)tok * 512 + e8, embg + (size_t)w * 512 + e8);
        return;
    }
    g -= 40960;
    if (g < 2048) {
        *(float4*)(cbuf + g * 8) = make_float4(0.f, 0.f, 0.f, 0.f);
        *(float4*)(cbuf + g * 8 + 4) = make_float4(0.f, 0.f, 0.f, 0.f);
        return;
    }
    g -= 2048;
    if (g < 2048) { u16x8 z = {}; *(u16x8*)(hbf + g * 8) = z; }
}

// ---------------------------------------------------------------------------
// enc_proj = X(6272x2048) @ enc_W^T(2048x512) + enc_b, bf16 MFMA, f32 out.
// BM=64 x BN=128 tile, 4 waves x (32r x 64c), BK=32, double-buffered LDS,
// global_load_lds width-16 staging, K-split x2 (grid z). Grid (98,4,2).
// kz=0 -> encproj (with bias); kz=1 -> scratch (= logits out buffer).
// ---------------------------------------------------------------------------
__global__ __launch_bounds__(256) void k_encproj(const u16* __restrict__ Xbf,
                                                 const u16* __restrict__ Wencbf,
                                                 const float* __restrict__ enc_b,
                                                 float* __restrict__ encproj,
                                                 float* __restrict__ scratch) {
    __shared__ u16 As[2][64 * 32];    // 4 KB per buf
    __shared__ u16 Bs[2][128 * 32];   // 8 KB per buf
    int tid = threadIdx.x, lane = tid & 63, w = tid >> 6;
    int wr = w >> 1, wc = w & 1;                 // wave -> 32x64 sub-tile
    int i0 = blockIdx.x * 64, j0 = blockIdx.y * 128;
    int kbase = blockIdx.z * 1024;               // K-split 0..1
    int ar = lane & 15, kg = lane >> 4;          // fragment row / k-group

    int srow = tid >> 2;                 // 0..63
    int sc = (tid & 3) * 8;              // u16 col within 32
    const u16* gA  = Xbf + (size_t)(i0 + srow) * NE + kbase + sc;
    const u16* gB0 = Wencbf + (size_t)(j0 + srow) * NE + kbase + sc;
    const u16* gB1 = Wencbf + (size_t)(j0 + 64 + srow) * NE + kbase + sc;

    f32x4 acc[2][4] = {};

#define STAGE_EP(buf, k0)                                   \
    do {                                                    \
        gld16(gA + (k0), &As[buf][tid * 8]);                \
        gld16(gB0 + (k0), &Bs[buf][tid * 8]);               \
        gld16(gB1 + (k0), &Bs[buf][2048 + tid * 8]);        \
    } while (0)

    STAGE_EP(0, 0);
    __syncthreads();
    for (int ks = 0; ks < 32; ++ks) {
        int cur = ks & 1;
        if (ks < 31) STAGE_EP(cur ^ 1, (ks + 1) * 32);
        bf8 a[2], b[4];
#pragma unroll
        for (int m = 0; m < 2; ++m)
            a[m] = *(const bf8*)(&As[cur][(wr * 32 + m * 16 + ar) * 32 + kg * 8]);
#pragma unroll
        for (int n = 0; n < 4; ++n)
            b[n] = *(const bf8*)(&Bs[cur][(wc * 64 + n * 16 + ar) * 32 + kg * 8]);
#pragma unroll
        for (int m = 0; m < 2; ++m)
#pragma unroll
            for (int n = 0; n < 4; ++n)
                acc[m][n] = __builtin_amdgcn_mfma_f32_16x16x32_bf16(a[m], b[n], acc[m][n], 0, 0, 0);
        if (ks < 31) __syncthreads();
    }
#undef STAGE_EP

    float* dst = (blockIdx.z == 0) ? encproj : scratch;
    int rbase = kg * 4;
#pragma unroll
    for (int m = 0; m < 2; ++m) {
        int row = i0 + wr * 32 + m * 16 + rbase;
#pragma unroll
        for (int n = 0; n < 4; ++n) {
            int col = j0 + wc * 64 + n * 16 + ar;
            float bias = (blockIdx.z == 0) ? enc_b[col] : 0.f;
#pragma unroll
            for (int r = 0; r < 4; ++r)
                dst[(size_t)(row + r) * AA + col] = acc[m][n][r] + bias;
        }
    }
}

// ---------------------------------------------------------------------------
// reduce the enc_proj K-partial: encproj += scratch  (3,211,264 f32)
// ---------------------------------------------------------------------------
__global__ __launch_bounds__(256) void k_epred(float* __restrict__ encproj,
                                               const float* __restrict__ scratch) {
    long i = ((long)blockIdx.x * 256 + threadIdx.x) * 4;
    f32x4 v = *(const f32x4*)(encproj + i);
    v += *(const f32x4*)(scratch + i);
    *(f32x4*)(encproj + i) = v;
}

// ---------------------------------------------------------------------------
// XW = X(6272x2048) @ Wctx^T (2048x2048) -> bf16, where Wctx = W_ih[:,512:].
// Precomputed once; per-step gate contribution becomes a cheap weighted sum:
// gates_ctx[b,j] = sum_p alpha[b,p] * XW[b,p,j]   (exact linearity identity).
// Grid (98,16) = 1568 blocks, BM=64 x BN=128, K=2048, no K-split needed.
// ---------------------------------------------------------------------------
__global__ __launch_bounds__(256) void k_xw(const u16* __restrict__ Xbf,
                                            const u16* __restrict__ Wihbf,
                                            u16* __restrict__ XWbf) {
    __shared__ u16 As[2][64 * 32];
    __shared__ u16 Bs[2][128 * 32];
    int tid = threadIdx.x, lane = tid & 63, w = tid >> 6;
    int wr = w >> 1, wc = w & 1;
    int i0 = blockIdx.x * 64, j0 = blockIdx.y * 128;
    int ar = lane & 15, kg = lane >> 4;

    int srow = tid >> 2;
    int sc = (tid & 3) * 8;
    const u16* gA  = Xbf + (size_t)(i0 + srow) * NE + sc;
    const u16* gB0 = Wihbf + (size_t)(j0 + srow) * 2560 + 512 + sc;
    const u16* gB1 = Wihbf + (size_t)(j0 + 64 + srow) * 2560 + 512 + sc;

    f32x4 acc[2][4] = {};

#define STAGE_XW(buf, k0)                                   \
    do {                                                    \
        gld16(gA + (k0), &As[buf][tid * 8]);                \
        gld16(gB0 + (k0), &Bs[buf][tid * 8]);               \
        gld16(gB1 + (k0), &Bs[buf][2048 + tid * 8]);        \
    } while (0)

    STAGE_XW(0, 0);
    __syncthreads();
    for (int ks = 0; ks < 64; ++ks) {
        int cur = ks & 1;
        if (ks < 63) STAGE_XW(cur ^ 1, (ks + 1) * 32);
        bf8 a[2], b[4];
#pragma unroll
        for (int m = 0; m < 2; ++m)
            a[m] = *(const bf8*)(&As[cur][(wr * 32 + m * 16 + ar) * 32 + kg * 8]);
#pragma unroll
        for (int n = 0; n < 4; ++n)
            b[n] = *(const bf8*)(&Bs[cur][(wc * 64 + n * 16 + ar) * 32 + kg * 8]);
#pragma unroll
        for (int m = 0; m < 2; ++m)
#pragma unroll
            for (int n = 0; n < 4; ++n)
                acc[m][n] = __builtin_amdgcn_mfma_f32_16x16x32_bf16(a[m], b[n], acc[m][n], 0, 0, 0);
        if (ks < 63) __syncthreads();
    }
#undef STAGE_XW

    int rbase = kg * 4;
#pragma unroll
    for (int m = 0; m < 2; ++m) {
        int row = i0 + wr * 32 + m * 16 + rbase;
#pragma unroll
        for (int n = 0; n < 4; ++n) {
            int col = j0 + wc * 64 + n * 16 + ar;
#pragma unroll
            for (int r = 0; r < 4; ++r)
                XWbf[(size_t)(row + r) * 2048 + col] = f2bf(acc[m][n][r]);
        }
    }
}

// ---------------------------------------------------------------------------
// gpre = embg(640x512) @ Wemb^T -> f32[640][2048], Wemb = W_ih[:, 0:512].
// All timesteps' embedding gate-contribution, precomputed once. Grid (10,16).
// ---------------------------------------------------------------------------
__global__ __launch_bounds__(256) void k_gpre(const u16* __restrict__ embg,
                                              const u16* __restrict__ Wihbf,
                                              float* __restrict__ gpre) {
    __shared__ u16 As[2][64 * 32];
    __shared__ u16 Bs[2][128 * 32];
    int tid = threadIdx.x, lane = tid & 63, w = tid >> 6;
    int wr = w >> 1, wc = w & 1;
    int i0 = blockIdx.x * 64, j0 = blockIdx.y * 128;
    int ar = lane & 15, kg = lane >> 4;

    int srow = tid >> 2;
    int sc = (tid & 3) * 8;
    const u16* gA  = embg + (size_t)(i0 + srow) * 512 + sc;
    const u16* gB0 = Wihbf + (size_t)(j0 + srow) * 2560 + sc;
    const u16* gB1 = Wihbf + (size_t)(j0 + 64 + srow) * 2560 + sc;

    f32x4 acc[2][4] = {};

#define STAGE_GP(buf, k0)                                   \
    do {                                                    \
        gld16(gA + (k0), &As[buf][tid * 8]);                \
        gld16(gB0 + (k0), &Bs[buf][tid * 8]);               \
        gld16(gB1 + (k0), &Bs[buf][2048 + tid * 8]);        \
    } while (0)

    STAGE_GP(0, 0);
    __syncthreads();
    for (int ks = 0; ks < 16; ++ks) {
        int cur = ks & 1;
        if (ks < 15) STAGE_GP(cur ^ 1, (ks + 1) * 32);
        bf8 a[2], b[4];
#pragma unroll
        for (int m = 0; m < 2; ++m)
            a[m] = *(const bf8*)(&As[cur][(wr * 32 + m * 16 + ar) * 32 + kg * 8]);
#pragma unroll
        for (int n = 0; n < 4; ++n)
            b[n] = *(const bf8*)(&Bs[cur][(wc * 64 + n * 16 + ar) * 32 + kg * 8]);
#pragma unroll
        for (int m = 0; m < 2; ++m)
#pragma unroll
            for (int n = 0; n < 4; ++n)
                acc[m][n] = __builtin_amdgcn_mfma_f32_16x16x32_bf16(a[m], b[n], acc[m][n], 0, 0, 0);
        if (ks < 15) __syncthreads();
    }
#undef STAGE_GP

    int rbase = kg * 4;
#pragma unroll
    for (int m = 0; m < 2; ++m) {
        int row = i0 + wr * 32 + m * 16 + rbase;
#pragma unroll
        for (int n = 0; n < 4; ++n) {
            int col = j0 + wc * 64 + n * 16 + ar;
#pragma unroll
            for (int r = 0; r < 4; ++r)
                gpre[(size_t)(row + r) * 2048 + col] = acc[m][n][r];
        }
    }
}

// ---------------------------------------------------------------------------
// per-step h-projections (one launch, both depend only on h):
//   waves 0..63  : dec_proj partials  dpart[4][32][512]   (r5 k_decproj body)
//   waves 64..319: ghh partials       ghh[4][32][2048] = h @ W_hh^T (k-split 4)
// Grid 80 blocks x 256 thr; blocks 0-15 pure decproj, 16-79 pure ghh.
// ---------------------------------------------------------------------------
__global__ __launch_bounds__(256) void k_hproj(const u16* __restrict__ hbf,
                                               const u16* __restrict__ decWbf,
                                               const u16* __restrict__ Whhbf,
                                               float* __restrict__ dpart,
                                               float* __restrict__ ghh) {
    int tid = threadIdx.x, lane = tid & 63;
    int ww = blockIdx.x * 4 + (tid >> 6);
    int ar = lane & 15, kg = lane >> 4, koff = kg * 8;
    if (ww < 64) {
        int ks = ww >> 4, rem = ww & 15, rg = rem >> 3, cg = rem & 7;
        const u16* Arow = hbf + (rg * 16 + ar) * HH + koff + ks * 128;
        f32x4 acc[4] = {};
#pragma unroll
        for (int s = 0; s < 4; ++s) {
            int k0 = s * 32;
            bf8 a = *(const bf8*)(Arow + k0);
#pragma unroll
            for (int jt = 0; jt < 4; ++jt) {
                bf8 b = *(const bf8*)(decWbf + (cg * 64 + jt * 16 + ar) * HH + ks * 128 + k0 + koff);
                acc[jt] = __builtin_amdgcn_mfma_f32_16x16x32_bf16(a, b, acc[jt], 0, 0, 0);
            }
        }
        int bb = rg * 16 + kg * 4;
#pragma unroll
        for (int jt = 0; jt < 4; ++jt) {
            int col = cg * 64 + jt * 16 + ar;
#pragma unroll
            for (int r = 0; r < 4; ++r)
                dpart[(ks * NB + bb + r) * AA + col] = acc[jt][r];
        }
    } else {
        int q = ww - 64;                       // 0..255
        int ks2 = q >> 6, rem = q & 63, cg = rem & 31, rg = rem >> 5;
        const u16* Arow = hbf + (rg * 16 + ar) * HH + ks2 * 128 + koff;
        f32x4 acc[4] = {};
#pragma unroll
        for (int s = 0; s < 4; ++s) {
            int k0 = s * 32;
            bf8 a = *(const bf8*)(Arow + k0);
#pragma unroll
            for (int jt = 0; jt < 4; ++jt) {
                int c = cg * 64 + jt * 16 + ar;
                bf8 b = *(const bf8*)(Whhbf + (size_t)c * HH + ks2 * 128 + k0 + koff);
                acc[jt] = __builtin_amdgcn_mfma_f32_16x16x32_bf16(a, b, acc[jt], 0, 0, 0);
            }
        }
        int bb = rg * 16 + kg * 4;
#pragma unroll
        for (int jt = 0; jt < 4; ++jt) {
            int col = cg * 64 + jt * 16 + ar;
#pragma unroll
            for (int r = 0; r < 4; ++r)
                ghh[(size_t)(ks2 * NB + bb + r) * 2048 + col] = acc[jt][r];
        }
    }
}

// ---------------------------------------------------------------------------
// attexp[b,p] = exp(att_b + sum_a att_W[a]*tanh(enc_proj[b,p,a]+dec_proj[b,a]))
// No atomic (round-4 lesson); denominator computed locally in k_ctxg.
// No max-shift: |att| bounded (~3), softmax shift-invariant -> exact.
// ---------------------------------------------------------------------------
__global__ __launch_bounds__(256) void k_attexp(const float* __restrict__ encproj,
                                                const float* __restrict__ dpart,
                                                const float* __restrict__ dec_b,
                                                const float* __restrict__ att_W,
                                                const float* __restrict__ att_b,
                                                float* __restrict__ attb) {
    int tid = threadIdx.x, lane = tid & 63;
    int row = blockIdx.x * 4 + (tid >> 6);
    int b = row / NP;
    const f32x4* ep = (const f32x4*)(encproj + (size_t)row * AA);
    const f32x4* d0 = (const f32x4*)(dpart + b * AA);
    const f32x4* d1 = (const f32x4*)(dpart + (NB + b) * AA);
    const f32x4* d2 = (const f32x4*)(dpart + (2 * NB + b) * AA);
    const f32x4* d3 = (const f32x4*)(dpart + (3 * NB + b) * AA);
    const f32x4* db = (const f32x4*)dec_b;
    const f32x4* aw = (const f32x4*)att_W;
    float s = 0.f;
#pragma unroll
    for (int h = 0; h < 2; ++h) {
        int ix = h * 64 + lane;
        f32x4 x = ep[ix];
        f32x4 d = d0[ix] + d1[ix] + d2[ix] + d3[ix] + db[ix];
        f32x4 wv = aw[ix];
        s += tanhf(x[0] + d[0]) * wv[0] + tanhf(x[1] + d[1]) * wv[1] +
             tanhf(x[2] + d[2]) * wv[2] + tanhf(x[3] + d[3]) * wv[3];
    }
#pragma unroll
    for (int off = 32; off > 0; off >>= 1) s += __shfl_down(s, off, 64);
    if (lane == 0) attb[row] = expf(s + att_b[0]);
}

// ---------------------------------------------------------------------------
// gate-contribution of context, directly: gctx[b,j] =
//   (sum_p attb[b,p] * XW[b,p,j]) / (sum_p attb[b,p])     (f32 out)
// grid (32 b x 16 chunks) x 512 thr; local denominator reduce, LDS reduce.
// Replaces BOTH old k_ctx and the per-step 2048-wide gates GEMM.
// ---------------------------------------------------------------------------
__global__ __launch_bounds__(512) void k_ctxg(const float* __restrict__ attb,
                                              const u16* __restrict__ XWbf,
                                              float* __restrict__ gctx) {
    int b = blockIdx.x >> 4, chunk = blockIdx.x & 15;
    int tid = threadIdx.x;
    __shared__ float sa[NP];
    __shared__ float sred[4][128];
    __shared__ float ssum;
    if (tid < NP) sa[tid] = attb[b * NP + tid];
    __syncthreads();
    if (tid < 64) {
        float s = 0.f;
        for (int p = tid; p < NP; p += 64) s += sa[p];
#pragma unroll
        for (int off = 32; off > 0; off >>= 1) s += __shfl_down(s, off, 64);
        if (tid == 0) ssum = s;
    }
    __syncthreads();
    float inv = 1.f / ssum;
    int col_l = tid & 127, pg = tid >> 7;
    int col = chunk * 128 + col_l;
    const u16* e = XWbf + (size_t)(b * NP + pg * 49) * 2048 + col;
    float acc = 0.f;
#pragma unroll 7
    for (int p = 0; p < 49; ++p) acc += sa[pg * 49 + p] * bf2f(e[(size_t)p * 2048]);
    sred[pg][col_l] = acc;
    __syncthreads();
    if (tid < 128) {
        float v = (sred[0][tid] + sred[1][tid] + sred[2][tid] + sred[3][tid]) * inv;
        gctx[(size_t)b * 2048 + chunk * 128 + tid] = v;
    }
}

// ---------------------------------------------------------------------------
// LSTM cell: g = gpre[t] + sum ghh partials + gctx + biases; activations;
// update c; h -> hbf (current) + hallbf[t].
// ---------------------------------------------------------------------------
__global__ void k_cell(const float* __restrict__ gpre, const float* __restrict__ ghh,
                       const float* __restrict__ gctx, const float* __restrict__ b_ih,
                       const float* __restrict__ b_hh, float* __restrict__ cbuf,
                       u16* __restrict__ hbf, u16* __restrict__ hallbf, int t) {
    int idx = blockIdx.x * 256 + threadIdx.x;   // 16384
    int b = idx >> 9, j = idx & 511;
    float g4[4];
#pragma unroll
    for (int q = 0; q < 4; ++q) {
        int col = j + q * 512;
        float s = b_ih[col] + b_hh[col]
                + gpre[((size_t)b * 20 + t) * 2048 + col]
                + gctx[(size_t)b * 2048 + col];
#pragma unroll
        for (int ks = 0; ks < 4; ++ks) s += ghh[(size_t)(ks * NB + b) * 2048 + col];
        g4[q] = s;
    }
    float si = 1.f / (1.f + expf(-g4[0]));
    float sf = 1.f / (1.f + expf(-g4[1]));
    float so = 1.f / (1.f + expf(-g4[3]));
    float c2 = sf * cbuf[idx] + si * tanhf(g4[2]);
    cbuf[idx] = c2;
    u16 hb = f2bf(so * tanhf(c2));
    hbf[b * 512 + j] = hb;
    hallbf[(b * 20 + t) * 512 + j] = hb;
}

// ---------------------------------------------------------------------------
// logits (batched over all t): hall(640x512) @ fc_W^T(512x10000) + fc_b
// m97 structure: 128x128 tile, 4 waves x 64x64, BK=32, double-buffered LDS,
// global_load_lds width-16 staging. Grid (5, 79); B-rows clamped at NV,
// epilogue stores only col < NV.
// ---------------------------------------------------------------------------
__global__ __launch_bounds__(256) void k_logits(const u16* __restrict__ hallbf,
                                                const u16* __restrict__ fcWbf,
                                                const float* __restrict__ fc_b,
                                                float* __restrict__ out) {
    __shared__ u16 As[2][128 * 32];
    __shared__ u16 Bs[2][128 * 32];
    int tid = threadIdx.x, lane = tid & 63, w = tid >> 6;
    int wr = w >> 1, wc = w & 1;
    int i0 = blockIdx.x * 128, j0 = blockIdx.y * 128;
    int ar = lane & 15, kg = lane >> 4;

    int srow = tid >> 2;                 // 0..63
    int sc = (tid & 3) * 8;              // u16 col within 32
    int brow0 = min(j0 + srow, NV - 1);        // clamp: keep reads in-bounds
    int brow1 = min(j0 + 64 + srow, NV - 1);
    const u16* gA0 = hallbf + (size_t)(i0 + srow) * HH + sc;
    const u16* gA1 = hallbf + (size_t)(i0 + 64 + srow) * HH + sc;
    const u16* gB0 = fcWbf + (size_t)brow0 * HH + sc;
    const u16* gB1 = fcWbf + (size_t)brow1 * HH + sc;

    f32x4 acc[4][4] = {};

#define STAGE_LG(buf, k0)                                   \
    do {                                                    \
        gld16(gA0 + (k0), &As[buf][tid * 8]);               \
        gld16(gA1 + (k0), &As[buf][2048 + tid * 8]);        \
        gld16(gB0 + (k0), &Bs[buf][tid * 8]);               \
        gld16(gB1 + (k0), &Bs[buf][2048 + tid * 8]);        \
    } while (0)

    STAGE_LG(0, 0);
    __syncthreads();
    for (int ks = 0; ks < 16; ++ks) {
        int cur = ks & 1;
        if (ks < 15) STAGE_LG(cur ^ 1, (ks + 1) * 32);
        bf8 a[4], b[4];
#pragma unroll
        for (int m = 0; m < 4; ++m)
            a[m] = *(const bf8*)(&As[cur][(wr * 64 + m * 16 + ar) * 32 + kg * 8]);
#pragma unroll
        for (int n = 0; n < 4; ++n)
            b[n] = *(const bf8*)(&Bs[cur][(wc * 64 + n * 16 + ar) * 32 + kg * 8]);
#pragma unroll
        for (int m = 0; m < 4; ++m)
#pragma unroll
            for (int n = 0; n < 4; ++n)
                acc[m][n] = __builtin_amdgcn_mfma_f32_16x16x32_bf16(a[m], b[n], acc[m][n], 0, 0, 0);
        if (ks < 15) __syncthreads();
    }
#undef STAGE_LG

    int rbase = kg * 4;
#pragma unroll
    for (int m = 0; m < 4; ++m) {
        int row = i0 + wr * 64 + m * 16 + rbase;
#pragma unroll
        for (int n = 0; n < 4; ++n) {
            int col = j0 + wc * 64 + n * 16 + ar;
            if (col < NV) {
                float bias = fc_b[col];
#pragma unroll
                for (int r = 0; r < 4; ++r)
                    out[(size_t)(row + r) * NV + col] = acc[m][n][r] + bias;
            }
        }
    }
}

// ---------------------------------------------------------------------------
extern "C" void kernel_launch(void* const* d_in, const int* in_sizes, int n_in,
                              void* d_out, int out_size, void* d_ws, size_t ws_size,
                              hipStream_t stream) {
    (void)in_sizes; (void)n_in; (void)out_size; (void)ws_size;
    const float* enc   = (const float*)d_in[0];
    const int*   caps  = (const int*)d_in[1];
    const float* emb   = (const float*)d_in[2];
    const float* enc_W = (const float*)d_in[3];
    const float* enc_b = (const float*)d_in[4];
    const float* dec_W = (const float*)d_in[5];
    const float* dec_b = (const float*)d_in[6];
    const float* att_W = (const float*)d_in[7];
    const float* att_b = (const float*)d_in[8];
    const float* W_ih  = (const float*)d_in[9];
    const float* W_hh  = (const float*)d_in[10];
    const float* b_ih  = (const float*)d_in[11];
    const float* b_hh  = (const float*)d_in[12];
    const float* fc_W  = (const float*)d_in[13];
    const float* fc_b  = (const float*)d_in[14];
    float* out = (float*)d_out;

    char* base = (char*)d_ws;
    float* encproj = (float*)base;                 base += (size_t)6272 * 512 * 4;
    float* dpart   = (float*)base;                 base += (size_t)4 * 32 * 512 * 4;
    float* attb    = (float*)base;                 base += (size_t)6272 * 4;
    float* cbuf    = (float*)base;                 base += (size_t)32 * 512 * 4;
    float* ghh     = (float*)base;                 base += (size_t)4 * 32 * 2048 * 4;
    float* gctx    = (float*)base;                 base += (size_t)32 * 2048 * 4;
    float* gpre    = (float*)base;                 base += (size_t)640 * 2048 * 4;
    u16* Xbf    = (u16*)base;                      base += (size_t)32 * 196 * 2048 * 2;
    u16* Wencbf = (u16*)base;                      base += (size_t)512 * 2048 * 2;
    u16* decWbf = (u16*)base;                      base += (size_t)512 * 512 * 2;
    u16* Wihbf  = (u16*)base;                      base += (size_t)2048 * 2560 * 2;
    u16* Whhbf  = (u16*)base;                      base += (size_t)2048 * 512 * 2;
    u16* fcWbf  = (u16*)base;                      base += (size_t)10000 * 512 * 2;
    u16* embg   = (u16*)base;                      base += (size_t)32 * 20 * 512 * 2;
    u16* XWbf   = (u16*)base;                      base += (size_t)6272 * 2048 * 2;
    u16* hbf    = (u16*)base;                      base += (size_t)32 * 512 * 2;
    u16* hallbf = (u16*)base;                      base += (size_t)32 * 20 * 512 * 2;

    k_convert<<<12660, 256, 0, stream>>>(enc, enc_W, dec_W, W_ih, W_hh, fc_W, emb, caps,
                                         Xbf, Wencbf, decWbf, Wihbf, Whhbf, fcWbf,
                                         embg, cbuf, hbf);
    k_encproj<<<dim3(98, 4, 2), 256, 0, stream>>>(Xbf, Wencbf, enc_b, encproj, out);
    k_epred<<<3136, 256, 0, stream>>>(encproj, out);
    k_xw<<<dim3(98, 16), 256, 0, stream>>>(Xbf, Wihbf, XWbf);
    k_gpre<<<dim3(10, 16), 256, 0, stream>>>(embg, Wihbf, gpre);
    for (int t = 0; t < NT; ++t) {
        k_hproj<<<80, 256, 0, stream>>>(hbf, decWbf, Whhbf, dpart, ghh);
        k_attexp<<<1568, 256, 0, stream>>>(encproj, dpart, dec_b, att_W, att_b, attb);
        k_ctxg<<<512, 512, 0, stream>>>(attb, XWbf, gctx);
        k_cell<<<64, 256, 0, stream>>>(gpre, ghh, gctx, b_ih, b_hh, cbuf, hbf,
                                       hallbf, t);
    }
    k_logits<<<dim3(5, 79), 256, 0, stream>>>(hallbf, fcWbf, fc_b, out);
}

// Round 9
// 539.382 us; speedup vs baseline: 4.3516x; 1.0605x over previous
//
#include <hip/hip_runtime.h>
#include <math.h>

typedef unsigned short u16;
typedef __attribute__((ext_vector_type(8))) short bf8;    // 8 bf16 in 4 VGPRs
typedef __attribute__((ext_vector_type(8))) unsigned short u16x8;
typedef __attribute__((ext_vector_type(4))) float f32x4;

constexpr int NB = 32;      // batch
constexpr int NP = 196;     // pixels
constexpr int NE = 2048;    // encoder dim
constexpr int ED = 512;     // embedding dim
constexpr int HH = 512;     // hidden
constexpr int AA = 512;     // attention dim
constexpr int NV = 10000;   // vocab
constexpr int NT = 20;      // timesteps

__device__ inline u16 f2bf(float f) {
    unsigned u = __builtin_bit_cast(unsigned, f);
    u += 0x7fffu + ((u >> 16) & 1u);          // RNE
    return (u16)(u >> 16);
}
__device__ inline float bf2f(u16 h) {
    return __builtin_bit_cast(float, (unsigned)h << 16);
}
__device__ inline void cvt8(const float* __restrict__ s, u16* __restrict__ d) {
    float4 v0 = *(const float4*)s, v1 = *(const float4*)(s + 4);
    u16x8 o;
    o[0] = f2bf(v0.x); o[1] = f2bf(v0.y); o[2] = f2bf(v0.z); o[3] = f2bf(v0.w);
    o[4] = f2bf(v1.x); o[5] = f2bf(v1.y); o[6] = f2bf(v1.z); o[7] = f2bf(v1.w);
    *(u16x8*)d = o;
}

// async global->LDS, 16 bytes per lane (global_load_lds_dwordx4)
__device__ inline void gld16(const u16* g, u16* l) {
    __builtin_amdgcn_global_load_lds(
        (const __attribute__((address_space(1))) void*)g,
        (__attribute__((address_space(3))) void*)l, 16, 0, 0);
}

// ---------------------------------------------------------------------------
// one-shot: convert X + all weights to bf16 (8 elems/thread), gather
// embeddings, zero c and h.
// ---------------------------------------------------------------------------
__global__ void k_convert(const float* __restrict__ enc, const float* __restrict__ enc_W,
                          const float* __restrict__ dec_W, const float* __restrict__ W_ih,
                          const float* __restrict__ W_hh, const float* __restrict__ fc_W,
                          const float* __restrict__ emb, const int* __restrict__ caps,
                          u16* __restrict__ Xbf, u16* __restrict__ Wencbf,
                          u16* __restrict__ decWbf, u16* __restrict__ Wihbf,
                          u16* __restrict__ Whhbf, u16* __restrict__ fcWbf,
                          u16* __restrict__ embg, float* __restrict__ cbuf,
                          u16* __restrict__ hbf) {
    long g = (long)blockIdx.x * 256 + threadIdx.x;   // 8-element groups
    if (g < 1605632) { cvt8(enc + g * 8, Xbf + g * 8); return; }
    g -= 1605632;
    if (g < 131072) { cvt8(enc_W + g * 8, Wencbf + g * 8); return; }
    g -= 131072;
    if (g < 32768) { cvt8(dec_W + g * 8, decWbf + g * 8); return; }
    g -= 32768;
    if (g < 655360) { cvt8(W_ih + g * 8, Wihbf + g * 8); return; }
    g -= 655360;
    if (g < 131072) { cvt8(W_hh + g * 8, Whhbf + g * 8); return; }
    g -= 131072;
    if (g < 640000) { cvt8(fc_W + g * 8, fcWbf + g * 8); return; }
    g -= 640000;
    if (g < 40960) {   // emb gather: embg[b][t][512]
        long w = g >> 6, e8 = (g & 63) * 8;
        long b = w / 20, t = w - b * 20;
        int tok = caps[b * 21 + t];
        cvt8(emb + (size_t)tok * 512 + e8, embg + (size_t)w * 512 + e8);
        return;
    }
    g -= 40960;
    if (g < 2048) {
        *(float4*)(cbuf + g * 8) = make_float4(0.f, 0.f, 0.f, 0.f);
        *(float4*)(cbuf + g * 8 + 4) = make_float4(0.f, 0.f, 0.f, 0.f);
        return;
    }
    g -= 2048;
    if (g < 2048) { u16x8 z = {}; *(u16x8*)(hbf + g * 8) = z; }
}

// ---------------------------------------------------------------------------
// MERGED front GEMM: [enc_proj | XW] = X(6272x2048) @ [enc_W ; Wctx]^T
// (N = 512 + 2048 = 2560). One pass over X replaces k_encproj+k_epred+k_xw.
// m97 structure: 128x128 tile, 4 waves x 64x64, BK=32, double-buffered LDS,
// global_load_lds width-16 staging. Grid (49, 20) = 980 blocks (3.8/CU).
// Region split at col 512 is a multiple of 128 -> all branches block-uniform:
//   j0 <  512: B = enc_W rows (stride 2048); out f32+enc_b -> encproj
//   j0 >= 512: B = W_ih rows, K-offset 512 (stride 2560); out bf16 -> XWbf
// ---------------------------------------------------------------------------
__global__ __launch_bounds__(256) void k_encxw(const u16* __restrict__ Xbf,
                                               const u16* __restrict__ Wencbf,
                                               const u16* __restrict__ Wihbf,
                                               const float* __restrict__ enc_b,
                                               float* __restrict__ encproj,
                                               u16* __restrict__ XWbf) {
    __shared__ u16 As[2][128 * 32];
    __shared__ u16 Bs[2][128 * 32];
    int tid = threadIdx.x, lane = tid & 63, w = tid >> 6;
    int wr = w >> 1, wc = w & 1;
    int i0 = blockIdx.x * 128, j0 = blockIdx.y * 128;
    int ar = lane & 15, kg = lane >> 4;

    int srow = tid >> 2;                 // 0..63
    int sc = (tid & 3) * 8;              // u16 col within 32
    const u16* gA0 = Xbf + (size_t)(i0 + srow) * NE + sc;
    const u16* gA1 = gA0 + (size_t)64 * NE;
    size_t bstr;
    const u16* gB0;
    if (j0 < 512) { bstr = 2048; gB0 = Wencbf + (size_t)(j0 + srow) * 2048 + sc; }
    else          { bstr = 2560; gB0 = Wihbf + (size_t)(j0 - 512 + srow) * 2560 + 512 + sc; }
    const u16* gB1 = gB0 + 64 * bstr;

    f32x4 acc[4][4] = {};

#define STAGE_EX(buf, k0)                                   \
    do {                                                    \
        gld16(gA0 + (k0), &As[buf][tid * 8]);               \
        gld16(gA1 + (k0), &As[buf][2048 + tid * 8]);        \
        gld16(gB0 + (k0), &Bs[buf][tid * 8]);               \
        gld16(gB1 + (k0), &Bs[buf][2048 + tid * 8]);        \
    } while (0)

    STAGE_EX(0, 0);
    __syncthreads();
    for (int ks = 0; ks < 64; ++ks) {
        int cur = ks & 1;
        if (ks < 63) STAGE_EX(cur ^ 1, (ks + 1) * 32);
        bf8 a[4], b[4];
#pragma unroll
        for (int m = 0; m < 4; ++m)
            a[m] = *(const bf8*)(&As[cur][(wr * 64 + m * 16 + ar) * 32 + kg * 8]);
#pragma unroll
        for (int n = 0; n < 4; ++n)
            b[n] = *(const bf8*)(&Bs[cur][(wc * 64 + n * 16 + ar) * 32 + kg * 8]);
#pragma unroll
        for (int m = 0; m < 4; ++m)
#pragma unroll
            for (int n = 0; n < 4; ++n)
                acc[m][n] = __builtin_amdgcn_mfma_f32_16x16x32_bf16(a[m], b[n], acc[m][n], 0, 0, 0);
        if (ks < 63) __syncthreads();
    }
#undef STAGE_EX

    int rbase = kg * 4;
    if (j0 < 512) {
#pragma unroll
        for (int m = 0; m < 4; ++m) {
            int row = i0 + wr * 64 + m * 16 + rbase;
#pragma unroll
            for (int n = 0; n < 4; ++n) {
                int col = j0 + wc * 64 + n * 16 + ar;
                float bias = enc_b[col];
#pragma unroll
                for (int r = 0; r < 4; ++r)
                    encproj[(size_t)(row + r) * AA + col] = acc[m][n][r] + bias;
            }
        }
    } else {
#pragma unroll
        for (int m = 0; m < 4; ++m) {
            int row = i0 + wr * 64 + m * 16 + rbase;
#pragma unroll
            for (int n = 0; n < 4; ++n) {
                int col = j0 - 512 + wc * 64 + n * 16 + ar;
#pragma unroll
                for (int r = 0; r < 4; ++r)
                    XWbf[(size_t)(row + r) * 2048 + col] = f2bf(acc[m][n][r]);
            }
        }
    }
}

// ---------------------------------------------------------------------------
// gpre = embg(640x512) @ Wemb^T -> f32[640][2048], Wemb = W_ih[:, 0:512].
// All timesteps' embedding gate-contribution, precomputed once. Grid (10,16).
// ---------------------------------------------------------------------------
__global__ __launch_bounds__(256) void k_gpre(const u16* __restrict__ embg,
                                              const u16* __restrict__ Wihbf,
                                              float* __restrict__ gpre) {
    __shared__ u16 As[2][64 * 32];
    __shared__ u16 Bs[2][128 * 32];
    int tid = threadIdx.x, lane = tid & 63, w = tid >> 6;
    int wr = w >> 1, wc = w & 1;
    int i0 = blockIdx.x * 64, j0 = blockIdx.y * 128;
    int ar = lane & 15, kg = lane >> 4;

    int srow = tid >> 2;
    int sc = (tid & 3) * 8;
    const u16* gA  = embg + (size_t)(i0 + srow) * 512 + sc;
    const u16* gB0 = Wihbf + (size_t)(j0 + srow) * 2560 + sc;
    const u16* gB1 = Wihbf + (size_t)(j0 + 64 + srow) * 2560 + sc;

    f32x4 acc[2][4] = {};

#define STAGE_GP(buf, k0)                                   \
    do {                                                    \
        gld16(gA + (k0), &As[buf][tid * 8]);                \
        gld16(gB0 + (k0), &Bs[buf][tid * 8]);               \
        gld16(gB1 + (k0), &Bs[buf][2048 + tid * 8]);        \
    } while (0)

    STAGE_GP(0, 0);
    __syncthreads();
    for (int ks = 0; ks < 16; ++ks) {
        int cur = ks & 1;
        if (ks < 15) STAGE_GP(cur ^ 1, (ks + 1) * 32);
        bf8 a[2], b[4];
#pragma unroll
        for (int m = 0; m < 2; ++m)
            a[m] = *(const bf8*)(&As[cur][(wr * 32 + m * 16 + ar) * 32 + kg * 8]);
#pragma unroll
        for (int n = 0; n < 4; ++n)
            b[n] = *(const bf8*)(&Bs[cur][(wc * 64 + n * 16 + ar) * 32 + kg * 8]);
#pragma unroll
        for (int m = 0; m < 2; ++m)
#pragma unroll
            for (int n = 0; n < 4; ++n)
                acc[m][n] = __builtin_amdgcn_mfma_f32_16x16x32_bf16(a[m], b[n], acc[m][n], 0, 0, 0);
        if (ks < 15) __syncthreads();
    }
#undef STAGE_GP

    int rbase = kg * 4;
#pragma unroll
    for (int m = 0; m < 2; ++m) {
        int row = i0 + wr * 32 + m * 16 + rbase;
#pragma unroll
        for (int n = 0; n < 4; ++n) {
            int col = j0 + wc * 64 + n * 16 + ar;
#pragma unroll
            for (int r = 0; r < 4; ++r)
                gpre[(size_t)(row + r) * 2048 + col] = acc[m][n][r];
        }
    }
}

// ---------------------------------------------------------------------------
// per-step h-projections (one launch, both depend only on h):
//   waves 0..63  : dec_proj partials  dpart[4][32][512]
//   waves 64..319: ghh partials       ghh[4][32][2048] = h @ W_hh^T (k-split 4)
// Grid 80 blocks x 256 thr; blocks 0-15 pure decproj, 16-79 pure ghh.
// ---------------------------------------------------------------------------
__global__ __launch_bounds__(256) void k_hproj(const u16* __restrict__ hbf,
                                               const u16* __restrict__ decWbf,
                                               const u16* __restrict__ Whhbf,
                                               float* __restrict__ dpart,
                                               float* __restrict__ ghh) {
    int tid = threadIdx.x, lane = tid & 63;
    int ww = blockIdx.x * 4 + (tid >> 6);
    int ar = lane & 15, kg = lane >> 4, koff = kg * 8;
    if (ww < 64) {
        int ks = ww >> 4, rem = ww & 15, rg = rem >> 3, cg = rem & 7;
        const u16* Arow = hbf + (rg * 16 + ar) * HH + koff + ks * 128;
        f32x4 acc[4] = {};
#pragma unroll
        for (int s = 0; s < 4; ++s) {
            int k0 = s * 32;
            bf8 a = *(const bf8*)(Arow + k0);
#pragma unroll
            for (int jt = 0; jt < 4; ++jt) {
                bf8 b = *(const bf8*)(decWbf + (cg * 64 + jt * 16 + ar) * HH + ks * 128 + k0 + koff);
                acc[jt] = __builtin_amdgcn_mfma_f32_16x16x32_bf16(a, b, acc[jt], 0, 0, 0);
            }
        }
        int bb = rg * 16 + kg * 4;
#pragma unroll
        for (int jt = 0; jt < 4; ++jt) {
            int col = cg * 64 + jt * 16 + ar;
#pragma unroll
            for (int r = 0; r < 4; ++r)
                dpart[(ks * NB + bb + r) * AA + col] = acc[jt][r];
        }
    } else {
        int q = ww - 64;                       // 0..255
        int ks2 = q >> 6, rem = q & 63, cg = rem & 31, rg = rem >> 5;
        const u16* Arow = hbf + (rg * 16 + ar) * HH + ks2 * 128 + koff;
        f32x4 acc[4] = {};
#pragma unroll
        for (int s = 0; s < 4; ++s) {
            int k0 = s * 32;
            bf8 a = *(const bf8*)(Arow + k0);
#pragma unroll
            for (int jt = 0; jt < 4; ++jt) {
                int c = cg * 64 + jt * 16 + ar;
                bf8 b = *(const bf8*)(Whhbf + (size_t)c * HH + ks2 * 128 + k0 + koff);
                acc[jt] = __builtin_amdgcn_mfma_f32_16x16x32_bf16(a, b, acc[jt], 0, 0, 0);
            }
        }
        int bb = rg * 16 + kg * 4;
#pragma unroll
        for (int jt = 0; jt < 4; ++jt) {
            int col = cg * 64 + jt * 16 + ar;
#pragma unroll
            for (int r = 0; r < 4; ++r)
                ghh[(size_t)(ks2 * NB + bb + r) * 2048 + col] = acc[jt][r];
        }
    }
}

// ---------------------------------------------------------------------------
// attexp[b,p] = exp(att_b + sum_a att_W[a]*tanh(enc_proj[b,p,a]+dec_proj[b,a]))
// No atomic (round-4 lesson); denominator computed locally in k_ctxg.
// No max-shift: |att| bounded (~3), softmax shift-invariant -> exact.
// ---------------------------------------------------------------------------
__global__ __launch_bounds__(256) void k_attexp(const float* __restrict__ encproj,
                                                const float* __restrict__ dpart,
                                                const float* __restrict__ dec_b,
                                                const float* __restrict__ att_W,
                                                const float* __restrict__ att_b,
                                                float* __restrict__ attb) {
    int tid = threadIdx.x, lane = tid & 63;
    int row = blockIdx.x * 4 + (tid >> 6);
    int b = row / NP;
    const f32x4* ep = (const f32x4*)(encproj + (size_t)row * AA);
    const f32x4* d0 = (const f32x4*)(dpart + b * AA);
    const f32x4* d1 = (const f32x4*)(dpart + (NB + b) * AA);
    const f32x4* d2 = (const f32x4*)(dpart + (2 * NB + b) * AA);
    const f32x4* d3 = (const f32x4*)(dpart + (3 * NB + b) * AA);
    const f32x4* db = (const f32x4*)dec_b;
    const f32x4* aw = (const f32x4*)att_W;
    float s = 0.f;
#pragma unroll
    for (int h = 0; h < 2; ++h) {
        int ix = h * 64 + lane;
        f32x4 x = ep[ix];
        f32x4 d = d0[ix] + d1[ix] + d2[ix] + d3[ix] + db[ix];
        f32x4 wv = aw[ix];
        s += tanhf(x[0] + d[0]) * wv[0] + tanhf(x[1] + d[1]) * wv[1] +
             tanhf(x[2] + d[2]) * wv[2] + tanhf(x[3] + d[3]) * wv[3];
    }
#pragma unroll
    for (int off = 32; off > 0; off >>= 1) s += __shfl_down(s, off, 64);
    if (lane == 0) attb[row] = expf(s + att_b[0]);
}

// ---------------------------------------------------------------------------
// gate-contribution of context, directly: gctx[b,j] =
//   (sum_p attb[b,p] * XW[b,p,j]) / (sum_p attb[b,p])     (f32 out)
// grid (32 b x 16 chunks) x 512 thr; local denominator reduce, LDS reduce.
// ---------------------------------------------------------------------------
__global__ __launch_bounds__(512) void k_ctxg(const float* __restrict__ attb,
                                              const u16* __restrict__ XWbf,
                                              float* __restrict__ gctx) {
    int b = blockIdx.x >> 4, chunk = blockIdx.x & 15;
    int tid = threadIdx.x;
    __shared__ float sa[NP];
    __shared__ float sred[4][128];
    __shared__ float ssum;
    if (tid < NP) sa[tid] = attb[b * NP + tid];
    __syncthreads();
    if (tid < 64) {
        float s = 0.f;
        for (int p = tid; p < NP; p += 64) s += sa[p];
#pragma unroll
        for (int off = 32; off > 0; off >>= 1) s += __shfl_down(s, off, 64);
        if (tid == 0) ssum = s;
    }
    __syncthreads();
    float inv = 1.f / ssum;
    int col_l = tid & 127, pg = tid >> 7;
    int col = chunk * 128 + col_l;
    const u16* e = XWbf + (size_t)(b * NP + pg * 49) * 2048 + col;
    float acc = 0.f;
#pragma unroll 7
    for (int p = 0; p < 49; ++p) acc += sa[pg * 49 + p] * bf2f(e[(size_t)p * 2048]);
    sred[pg][col_l] = acc;
    __syncthreads();
    if (tid < 128) {
        float v = (sred[0][tid] + sred[1][tid] + sred[2][tid] + sred[3][tid]) * inv;
        gctx[(size_t)b * 2048 + chunk * 128 + tid] = v;
    }
}

// ---------------------------------------------------------------------------
// LSTM cell: g = gpre[t] + sum ghh partials + gctx + biases; activations;
// update c; h -> hbf (current) + hallbf[t].
// ---------------------------------------------------------------------------
__global__ void k_cell(const float* __restrict__ gpre, const float* __restrict__ ghh,
                       const float* __restrict__ gctx, const float* __restrict__ b_ih,
                       const float* __restrict__ b_hh, float* __restrict__ cbuf,
                       u16* __restrict__ hbf, u16* __restrict__ hallbf, int t) {
    int idx = blockIdx.x * 256 + threadIdx.x;   // 16384
    int b = idx >> 9, j = idx & 511;
    float g4[4];
#pragma unroll
    for (int q = 0; q < 4; ++q) {
        int col = j + q * 512;
        float s = b_ih[col] + b_hh[col]
                + gpre[((size_t)b * 20 + t) * 2048 + col]
                + gctx[(size_t)b * 2048 + col];
#pragma unroll
        for (int ks = 0; ks < 4; ++ks) s += ghh[(size_t)(ks * NB + b) * 2048 + col];
        g4[q] = s;
    }
    float si = 1.f / (1.f + expf(-g4[0]));
    float sf = 1.f / (1.f + expf(-g4[1]));
    float so = 1.f / (1.f + expf(-g4[3]));
    float c2 = sf * cbuf[idx] + si * tanhf(g4[2]);
    cbuf[idx] = c2;
    u16 hb = f2bf(so * tanhf(c2));
    hbf[b * 512 + j] = hb;
    hallbf[(b * 20 + t) * 512 + j] = hb;
}

// ---------------------------------------------------------------------------
// logits (batched over all t): hall(640x512) @ fc_W^T(512x10000) + fc_b
// m97 structure: 128x128 tile, 4 waves x 64x64, BK=32, double-buffered LDS,
// global_load_lds width-16 staging. Grid (5, 79); B-rows clamped at NV,
// epilogue stores only col < NV.
// ---------------------------------------------------------------------------
__global__ __launch_bounds__(256) void k_logits(const u16* __restrict__ hallbf,
                                                const u16* __restrict__ fcWbf,
                                                const float* __restrict__ fc_b,
                                                float* __restrict__ out) {
    __shared__ u16 As[2][128 * 32];
    __shared__ u16 Bs[2][128 * 32];
    int tid = threadIdx.x, lane = tid & 63, w = tid >> 6;
    int wr = w >> 1, wc = w & 1;
    int i0 = blockIdx.x * 128, j0 = blockIdx.y * 128;
    int ar = lane & 15, kg = lane >> 4;

    int srow = tid >> 2;                 // 0..63
    int sc = (tid & 3) * 8;              // u16 col within 32
    int brow0 = min(j0 + srow, NV - 1);        // clamp: keep reads in-bounds
    int brow1 = min(j0 + 64 + srow, NV - 1);
    const u16* gA0 = hallbf + (size_t)(i0 + srow) * HH + sc;
    const u16* gA1 = hallbf + (size_t)(i0 + 64 + srow) * HH + sc;
    const u16* gB0 = fcWbf + (size_t)brow0 * HH + sc;
    const u16* gB1 = fcWbf + (size_t)brow1 * HH + sc;

    f32x4 acc[4][4] = {};

#define STAGE_LG(buf, k0)                                   \
    do {                                                    \
        gld16(gA0 + (k0), &As[buf][tid * 8]);               \
        gld16(gA1 + (k0), &As[buf][2048 + tid * 8]);        \
        gld16(gB0 + (k0), &Bs[buf][tid * 8]);               \
        gld16(gB1 + (k0), &Bs[buf][2048 + tid * 8]);        \
    } while (0)

    STAGE_LG(0, 0);
    __syncthreads();
    for (int ks = 0; ks < 16; ++ks) {
        int cur = ks & 1;
        if (ks < 15) STAGE_LG(cur ^ 1, (ks + 1) * 32);
        bf8 a[4], b[4];
#pragma unroll
        for (int m = 0; m < 4; ++m)
            a[m] = *(const bf8*)(&As[cur][(wr * 64 + m * 16 + ar) * 32 + kg * 8]);
#pragma unroll
        for (int n = 0; n < 4; ++n)
            b[n] = *(const bf8*)(&Bs[cur][(wc * 64 + n * 16 + ar) * 32 + kg * 8]);
#pragma unroll
        for (int m = 0; m < 4; ++m)
#pragma unroll
            for (int n = 0; n < 4; ++n)
                acc[m][n] = __builtin_amdgcn_mfma_f32_16x16x32_bf16(a[m], b[n], acc[m][n], 0, 0, 0);
        if (ks < 15) __syncthreads();
    }
#undef STAGE_LG

    int rbase = kg * 4;
#pragma unroll
    for (int m = 0; m < 4; ++m) {
        int row = i0 + wr * 64 + m * 16 + rbase;
#pragma unroll
        for (int n = 0; n < 4; ++n) {
            int col = j0 + wc * 64 + n * 16 + ar;
            if (col < NV) {
                float bias = fc_b[col];
#pragma unroll
                for (int r = 0; r < 4; ++r)
                    out[(size_t)(row + r) * NV + col] = acc[m][n][r] + bias;
            }
        }
    }
}

// ---------------------------------------------------------------------------
extern "C" void kernel_launch(void* const* d_in, const int* in_sizes, int n_in,
                              void* d_out, int out_size, void* d_ws, size_t ws_size,
                              hipStream_t stream) {
    (void)in_sizes; (void)n_in; (void)out_size; (void)ws_size;
    const float* enc   = (const float*)d_in[0];
    const int*   caps  = (const int*)d_in[1];
    const float* emb   = (const float*)d_in[2];
    const float* enc_W = (const float*)d_in[3];
    const float* enc_b = (const float*)d_in[4];
    const float* dec_W = (const float*)d_in[5];
    const float* dec_b = (const float*)d_in[6];
    const float* att_W = (const float*)d_in[7];
    const float* att_b = (const float*)d_in[8];
    const float* W_ih  = (const float*)d_in[9];
    const float* W_hh  = (const float*)d_in[10];
    const float* b_ih  = (const float*)d_in[11];
    const float* b_hh  = (const float*)d_in[12];
    const float* fc_W  = (const float*)d_in[13];
    const float* fc_b  = (const float*)d_in[14];
    float* out = (float*)d_out;

    char* base = (char*)d_ws;
    float* encproj = (float*)base;                 base += (size_t)6272 * 512 * 4;
    float* dpart   = (float*)base;                 base += (size_t)4 * 32 * 512 * 4;
    float* attb    = (float*)base;                 base += (size_t)6272 * 4;
    float* cbuf    = (float*)base;                 base += (size_t)32 * 512 * 4;
    float* ghh     = (float*)base;                 base += (size_t)4 * 32 * 2048 * 4;
    float* gctx    = (float*)base;                 base += (size_t)32 * 2048 * 4;
    float* gpre    = (float*)base;                 base += (size_t)640 * 2048 * 4;
    u16* Xbf    = (u16*)base;                      base += (size_t)32 * 196 * 2048 * 2;
    u16* Wencbf = (u16*)base;                      base += (size_t)512 * 2048 * 2;
    u16* decWbf = (u16*)base;                      base += (size_t)512 * 512 * 2;
    u16* Wihbf  = (u16*)base;                      base += (size_t)2048 * 2560 * 2;
    u16* Whhbf  = (u16*)base;                      base += (size_t)2048 * 512 * 2;
    u16* fcWbf  = (u16*)base;                      base += (size_t)10000 * 512 * 2;
    u16* embg   = (u16*)base;                      base += (size_t)32 * 20 * 512 * 2;
    u16* XWbf   = (u16*)base;                      base += (size_t)6272 * 2048 * 2;
    u16* hbf    = (u16*)base;                      base += (size_t)32 * 512 * 2;
    u16* hallbf = (u16*)base;                      base += (size_t)32 * 20 * 512 * 2;

    k_convert<<<12660, 256, 0, stream>>>(enc, enc_W, dec_W, W_ih, W_hh, fc_W, emb, caps,
                                         Xbf, Wencbf, decWbf, Wihbf, Whhbf, fcWbf,
                                         embg, cbuf, hbf);
    k_encxw<<<dim3(49, 20), 256, 0, stream>>>(Xbf, Wencbf, Wihbf, enc_b, encproj, XWbf);
    k_gpre<<<dim3(10, 16), 256, 0, stream>>>(embg, Wihbf, gpre);
    for (int t = 0; t < NT; ++t) {
        k_hproj<<<80, 256, 0, stream>>>(hbf, decWbf, Whhbf, dpart, ghh);
        k_attexp<<<1568, 256, 0, stream>>>(encproj, dpart, dec_b, att_W, att_b, attb);
        k_ctxg<<<512, 512, 0, stream>>>(attb, XWbf, gctx);
        k_cell<<<64, 256, 0, stream>>>(gpre, ghh, gctx, b_ih, b_hh, cbuf, hbf,
                                       hallbf, t);
    }
    k_logits<<<dim3(5, 79), 256, 0, stream>>>(hallbf, fcWbf, fc_b, out);
}